// Round 1
// baseline (1751.694 us; speedup 1.0000x reference)
//
#include <hip/hip_runtime.h>
#include <cmath>

#define NNODE 40000
#define NREL  2000
#define NTRI  600000
#define DIMK  128
#define F3    384
#define NPROX 64
#define EPSN  1e-12f

static __device__ __forceinline__ float waveSum(float v) {
#pragma unroll
    for (int m = 32; m >= 1; m >>= 1) v += __shfl_xor(v, m, 64);
    return v;
}

// ---------------- CSR build ----------------
__global__ void k_count(const int* __restrict__ row, int* __restrict__ deg) {
    int t = blockIdx.x * 256 + threadIdx.x;
    if (t < NTRI) atomicAdd(&deg[row[t]], 1);
}

__global__ void k_scan(const int* __restrict__ deg, int* __restrict__ off) {
    __shared__ int lds[1024];
    __shared__ int runS;
    int tid = threadIdx.x;
    if (tid == 0) runS = 0;
    __syncthreads();
    for (int base = 0; base < NNODE; base += 1024) {
        int i = base + tid;
        int v = (i < NNODE) ? deg[i] : 0;
        lds[tid] = v;
        __syncthreads();
        for (int s = 1; s < 1024; s <<= 1) {
            int t2 = (tid >= s) ? lds[tid - s] : 0;
            __syncthreads();
            lds[tid] += t2;
            __syncthreads();
        }
        int incl = lds[tid];
        if (i < NNODE) off[i] = runS + incl - v;
        int tot = lds[1023];
        __syncthreads();
        if (tid == 0) runS += tot;
        __syncthreads();
    }
    if (tid == 0) off[NNODE] = runS;
}

__global__ void k_place(const int* __restrict__ row, const int* __restrict__ off,
                        int* __restrict__ cur, int* __restrict__ perm) {
    int t = blockIdx.x * 256 + threadIdx.x;
    if (t < NTRI) {
        int r = row[t];
        int p = off[r] + atomicAdd(&cur[r], 1);
        perm[p] = t;
    }
}

// ---------------- small precomputes ----------------
// per-relation: norm and dot with the 4 attention vectors (e_l0,e_l1,r_l0,r_l1)
__global__ void k_relprep(const float* __restrict__ rel_emb,
                          const float* __restrict__ e_attn, const float* __restrict__ r_attn,
                          float* __restrict__ nrm, float* __restrict__ relAttn) {
    int r = blockIdx.x;
    int lane = threadIdx.x;
    float a = rel_emb[r * DIMK + lane];
    float b = rel_emb[r * DIMK + 64 + lane];
    float nn = waveSum(a * a + b * b);
    float d0 = waveSum(a * e_attn[lane] + b * e_attn[64 + lane]);
    float d1 = waveSum(a * e_attn[DIMK + lane] + b * e_attn[DIMK + 64 + lane]);
    float d2 = waveSum(a * r_attn[lane] + b * r_attn[64 + lane]);
    float d3 = waveSum(a * r_attn[DIMK + lane] + b * r_attn[DIMK + 64 + lane]);
    if (lane == 0) {
        nrm[r] = sqrtf(nn);
        relAttn[0 * NREL + r] = d0;
        relAttn[1 * NREL + r] = d1;
        relAttn[2 * NREL + r] = d2;
        relAttn[3 * NREL + r] = d3;
    }
}

// per-edge tri_rel scalar: l2norm(r_val * rel_row) = rel_row * scale
__global__ void k_scale(const int* __restrict__ ridx, const float* __restrict__ rval,
                        const float* __restrict__ nrm, float* __restrict__ scalev) {
    int t = blockIdx.x * 256 + threadIdx.x;
    if (t < NTRI) {
        float v = rval[t];
        float nn = fabsf(v) * nrm[ridx[t]];
        scalev[t] = v / fmaxf(nn, EPSN);
    }
}

// proxy rows l2-normalized and transposed -> pnT[384][64]
__global__ void k_proxyprep(const float* __restrict__ proxy, float* __restrict__ pnT) {
    int k = blockIdx.x;      // proxy row 0..63
    int lane = threadIdx.x;  // 0..63
    float v[6];
    float ss = 0.f;
#pragma unroll
    for (int j = 0; j < 6; j++) {
        v[j] = proxy[k * F3 + j * 64 + lane];
        ss += v[j] * v[j];
    }
    ss = waveSum(ss);
    float inv = 1.0f / fmaxf(sqrtf(ss), EPSN);
#pragma unroll
    for (int j = 0; j < 6; j++) pnT[(j * 64 + lane) * NPROX + k] = v[j] * inv;
}

// ---------------- neighbor mean + tanh (writes out slice 0) ----------------
__global__ void k_avg_tanh(const int* __restrict__ off, const int* __restrict__ perm,
                           const int* __restrict__ col, const float* __restrict__ emb,
                           float* __restrict__ outb) {
    int wid = (blockIdx.x * blockDim.x + threadIdx.x) >> 6;
    int lane = threadIdx.x & 63;
    if (wid >= NNODE) return;
    int e0 = off[wid], e1 = off[wid + 1];
    float a0 = 0.f, a1 = 0.f;
    for (int e = e0; e < e1; e++) {
        int c = col[perm[e]];
        const float* p = emb + (size_t)c * DIMK;
        a0 += p[lane];
        a1 += p[lane + 64];
    }
    float invd = (e1 > e0) ? 1.0f / (float)(e1 - e0) : 0.0f;
    float* op = outb + (size_t)wid * F3;
    op[lane] = tanhf(a0 * invd);
    op[lane + 64] = tanhf(a1 * invd);
}

// ---------------- relational-reflection attention aggregation ----------------
// read slice lin of outb, write slice lin+1
__global__ void k_agg(const int* __restrict__ off, const int* __restrict__ perm,
                      const int* __restrict__ col, const int* __restrict__ ridx,
                      const float* __restrict__ scalev, const float* __restrict__ attR,
                      const float* __restrict__ rel_emb, float* __restrict__ outb, int lin) {
    int wid = (blockIdx.x * blockDim.x + threadIdx.x) >> 6;
    int lane = threadIdx.x & 63;
    if (wid >= NNODE) return;
    int e0 = off[wid], e1 = off[wid + 1];
    float acc0 = 0.f, acc1 = 0.f, s = 0.f;
    const float* prev = outb + lin * DIMK;
    for (int e = e0; e < e1; e++) {
        int t = perm[e];
        int c = col[t];
        int r = ridx[t];
        float sc = scalev[t];
        float w = expf(sc * attR[r]);
        const float* fp = prev + (size_t)c * F3;
        float f0 = fp[lane], f1 = fp[lane + 64];
        const float* rp = rel_emb + (size_t)r * DIMK;
        float t0 = sc * rp[lane], t1 = sc * rp[lane + 64];
        float dot = waveSum(f0 * t0 + f1 * t1);
        acc0 += w * (f0 - 2.f * dot * t0);
        acc1 += w * (f1 - 2.f * dot * t1);
        s += w;
    }
    float invs = (e1 > e0) ? 1.f / s : 0.f;
    float* op = outb + (size_t)wid * F3 + (lin + 1) * DIMK;
    op[lane] = tanhf(acc0 * invs);
    op[lane + 64] = tanhf(acc1 * invs);
}

// ---------------- epilogue ----------------
__global__ void k_rnorm(const float* __restrict__ outb, float* __restrict__ rnorm) {
    int wid = (blockIdx.x * blockDim.x + threadIdx.x) >> 6;
    int lane = threadIdx.x & 63;
    if (wid >= NNODE) return;
    float ss = 0.f;
#pragma unroll
    for (int j = 0; j < 6; j++) {
        float v = outb[(size_t)wid * F3 + j * 64 + lane];
        ss += v * v;
    }
    ss = waveSum(ss);
    if (lane == 0) rnorm[wid] = 1.0f / fmaxf(sqrtf(ss), EPSN);
}

// scores = l2norm(out) @ proxynT  -> softmax rows -> pa [N][64]
__global__ void k_scores(const float* __restrict__ outb, const float* __restrict__ rnorm,
                         const float* __restrict__ pnT, float* __restrict__ pa) {
    __shared__ __align__(16) float As[16][68];
    __shared__ __align__(16) float Bs[16][68];
    __shared__ float Ss[64][65];
    int tid = threadIdx.x;
    int row0 = blockIdx.x * 64;
    int kk = tid & 15, rr = tid >> 4;
    int cb = tid & 63, kb = tid >> 6;
    int tx = tid & 15, ty = tid >> 4;
    int c0 = tx * 4, r0 = ty * 4;
    float acc[4][4] = {};
    for (int k0 = 0; k0 < F3; k0 += 16) {
#pragma unroll
        for (int u = 0; u < 4; u++) {
            int r = rr + u * 16;
            As[kk][r] = outb[(size_t)(row0 + r) * F3 + k0 + kk] * rnorm[row0 + r];
        }
#pragma unroll
        for (int u = 0; u < 4; u++) {
            int k = kb + u * 4;
            Bs[k][cb] = pnT[(size_t)(k0 + k) * NPROX + cb];
        }
        __syncthreads();
#pragma unroll
        for (int k = 0; k < 16; k++) {
            float4 av = *(const float4*)&As[k][r0];
            float4 bv = *(const float4*)&Bs[k][c0];
            float a[4] = {av.x, av.y, av.z, av.w};
            float b[4] = {bv.x, bv.y, bv.z, bv.w};
#pragma unroll
            for (int i = 0; i < 4; i++)
#pragma unroll
                for (int j = 0; j < 4; j++) acc[i][j] += a[i] * b[j];
        }
        __syncthreads();
    }
#pragma unroll
    for (int i = 0; i < 4; i++)
#pragma unroll
        for (int j = 0; j < 4; j++) Ss[r0 + i][c0 + j] = acc[i][j];
    __syncthreads();
    if (tid < 64) {
        int r = tid;
        float m = -1e30f;
        for (int c = 0; c < 64; c++) m = fmaxf(m, Ss[r][c]);
        float s = 0.f;
        for (int c = 0; c < 64; c++) s += expf(Ss[r][c] - m);
        float inv = 1.f / s;
        float* po = pa + (size_t)(row0 + r) * NPROX;
        for (int c = 0; c < 64; c++) po[c] = expf(Ss[r][c] - m) * inv;
    }
}

// pf = out - pa @ proxy     [N][384]
__global__ void k_pf(const float* __restrict__ pa, const float* __restrict__ proxy,
                     const float* __restrict__ outb, float* __restrict__ pf) {
    __shared__ __align__(16) float As[16][68];
    __shared__ __align__(16) float Bs[16][68];
    int tid = threadIdx.x;
    int row0 = blockIdx.x * 64;
    int col0 = blockIdx.y * 64;
    int kk = tid & 15, rr = tid >> 4;
    int cb = tid & 63, kb = tid >> 6;
    int tx = tid & 15, ty = tid >> 4;
    int c0 = tx * 4, r0 = ty * 4;
    float acc[4][4] = {};
    for (int k0 = 0; k0 < NPROX; k0 += 16) {
#pragma unroll
        for (int u = 0; u < 4; u++) {
            int r = rr + u * 16;
            As[kk][r] = pa[(size_t)(row0 + r) * NPROX + k0 + kk];
        }
#pragma unroll
        for (int u = 0; u < 4; u++) {
            int k = kb + u * 4;
            Bs[k][cb] = proxy[(size_t)(k0 + k) * F3 + col0 + cb];
        }
        __syncthreads();
#pragma unroll
        for (int k = 0; k < 16; k++) {
            float4 av = *(const float4*)&As[k][r0];
            float4 bv = *(const float4*)&Bs[k][c0];
            float a[4] = {av.x, av.y, av.z, av.w};
            float b[4] = {bv.x, bv.y, bv.z, bv.w};
#pragma unroll
            for (int i = 0; i < 4; i++)
#pragma unroll
                for (int j = 0; j < 4; j++) acc[i][j] += a[i] * b[j];
        }
        __syncthreads();
    }
#pragma unroll
    for (int i = 0; i < 4; i++)
#pragma unroll
        for (int j = 0; j < 4; j++) {
            size_t idx = (size_t)(row0 + r0 + i) * F3 + col0 + c0 + j;
            pf[idx] = outb[idx] - acc[i][j];
        }
}

// g = sigmoid(pf @ gate + bias); res = g*out + (1-g)*pf  -> d_out slice
__global__ void k_gate(const float* __restrict__ pf, const float* __restrict__ gate,
                       const float* __restrict__ bias, const float* __restrict__ outb,
                       float* __restrict__ dout, int outoff) {
    __shared__ __align__(16) float As[16][68];
    __shared__ __align__(16) float Bs[16][68];
    int tid = threadIdx.x;
    int row0 = blockIdx.x * 64;
    int col0 = blockIdx.y * 64;
    int kk = tid & 15, rr = tid >> 4;
    int cb = tid & 63, kb = tid >> 6;
    int tx = tid & 15, ty = tid >> 4;
    int c0 = tx * 4, r0 = ty * 4;
    float acc[4][4] = {};
    for (int k0 = 0; k0 < F3; k0 += 16) {
#pragma unroll
        for (int u = 0; u < 4; u++) {
            int r = rr + u * 16;
            As[kk][r] = pf[(size_t)(row0 + r) * F3 + k0 + kk];
        }
#pragma unroll
        for (int u = 0; u < 4; u++) {
            int k = kb + u * 4;
            Bs[k][cb] = gate[(size_t)(k0 + k) * F3 + col0 + cb];
        }
        __syncthreads();
#pragma unroll
        for (int k = 0; k < 16; k++) {
            float4 av = *(const float4*)&As[k][r0];
            float4 bv = *(const float4*)&Bs[k][c0];
            float a[4] = {av.x, av.y, av.z, av.w};
            float b[4] = {bv.x, bv.y, bv.z, bv.w};
#pragma unroll
            for (int i = 0; i < 4; i++)
#pragma unroll
                for (int j = 0; j < 4; j++) acc[i][j] += a[i] * b[j];
        }
        __syncthreads();
    }
#pragma unroll
    for (int i = 0; i < 4; i++)
#pragma unroll
        for (int j = 0; j < 4; j++) {
            int r = row0 + r0 + i, c = col0 + c0 + j;
            float x = acc[i][j] + bias[c];
            float g = 1.f / (1.f + expf(-x));
            size_t idx = (size_t)r * F3 + c;
            float o = outb[idx], p = pf[idx];
            dout[(size_t)r * 768 + outoff + c] = g * o + (1.f - g) * p;
        }
}

// ---------------- launch ----------------
extern "C" void kernel_launch(void* const* d_in, const int* in_sizes, int n_in,
                              void* d_out, int out_size, void* d_ws, size_t ws_size,
                              hipStream_t stream) {
    const int* ent_adj = (const int*)d_in[0];
    const int* rel_adj = (const int*)d_in[1];
    const int* adj_list = (const int*)d_in[4];
    const int* r_index = (const int*)d_in[5];
    const float* r_val = (const float*)d_in[6];
    const float* ent_emb = (const float*)d_in[9];
    const float* rel_emb = (const float*)d_in[10];
    const float* e_attn = (const float*)d_in[11];
    const float* e_gate = (const float*)d_in[12];
    const float* e_proxy = (const float*)d_in[13];
    const float* e_bias = (const float*)d_in[14];
    const float* r_attn = (const float*)d_in[15];
    const float* r_gate = (const float*)d_in[16];
    const float* r_proxy = (const float*)d_in[17];
    const float* r_bias = (const float*)d_in[18];
    float* out = (float*)d_out;

    char* ws = (char*)d_ws;
    size_t off = 0;
    auto alloc = [&](size_t bytes) -> void* {
        off = (off + 255) & ~(size_t)255;
        void* p = ws + off;
        off += bytes;
        return p;
    };

    int* degcur = (int*)alloc(6 * NNODE * sizeof(int));
    int* degA = degcur, *curA = degcur + NNODE;
    int* degE = degcur + 2 * NNODE, *curE = degcur + 3 * NNODE;
    int* degR = degcur + 4 * NNODE, *curR = degcur + 5 * NNODE;
    int* offA = (int*)alloc((NNODE + 1) * sizeof(int));
    int* offE = (int*)alloc((NNODE + 1) * sizeof(int));
    int* offR = (int*)alloc((NNODE + 1) * sizeof(int));
    int* permA = (int*)alloc(NTRI * sizeof(int));
    int* permE = (int*)alloc(NTRI * sizeof(int));
    int* permR = (int*)alloc(NTRI * sizeof(int));
    float* nrm = (float*)alloc(NREL * sizeof(float));
    float* relAttn = (float*)alloc(4 * NREL * sizeof(float));
    float* scalev = (float*)alloc(NTRI * sizeof(float));
    float* pnT_e = (float*)alloc((size_t)F3 * NPROX * sizeof(float));
    float* pnT_r = (float*)alloc((size_t)F3 * NPROX * sizeof(float));
    float* rnorm = (float*)alloc((size_t)NNODE * sizeof(float));
    float* pa = (float*)alloc((size_t)NNODE * NPROX * sizeof(float));
    float* pf = (float*)alloc((size_t)NNODE * F3 * sizeof(float));
    float* out_e = (float*)alloc((size_t)NNODE * F3 * sizeof(float));
    float* out_r = (float*)alloc((size_t)NNODE * F3 * sizeof(float));
    (void)ws_size; (void)in_sizes; (void)n_in; (void)out_size;

    hipMemsetAsync(degcur, 0, 6 * NNODE * sizeof(int), stream);

    int gT = (NTRI + 255) / 256;
    k_count<<<gT, 256, 0, stream>>>(adj_list, degA);
    k_count<<<gT, 256, 0, stream>>>(ent_adj, degE);
    k_count<<<gT, 256, 0, stream>>>(rel_adj, degR);
    k_scan<<<1, 1024, 0, stream>>>(degA, offA);
    k_scan<<<1, 1024, 0, stream>>>(degE, offE);
    k_scan<<<1, 1024, 0, stream>>>(degR, offR);
    k_place<<<gT, 256, 0, stream>>>(adj_list, offA, curA, permA);
    k_place<<<gT, 256, 0, stream>>>(ent_adj, offE, curE, permE);
    k_place<<<gT, 256, 0, stream>>>(rel_adj, offR, curR, permR);

    k_relprep<<<NREL, 64, 0, stream>>>(rel_emb, e_attn, r_attn, nrm, relAttn);
    k_scale<<<gT, 256, 0, stream>>>(r_index + NTRI, r_val, nrm, scalev);
    k_proxyprep<<<NPROX, 64, 0, stream>>>(e_proxy, pnT_e);
    k_proxyprep<<<NPROX, 64, 0, stream>>>(r_proxy, pnT_r);

    int gW = NNODE / 4;  // 4 waves (rows) per 256-thread block
    k_avg_tanh<<<gW, 256, 0, stream>>>(offE, permE, ent_adj + NTRI, ent_emb, out_e);
    k_avg_tanh<<<gW, 256, 0, stream>>>(offR, permR, rel_adj + NTRI, rel_emb, out_r);

    k_agg<<<gW, 256, 0, stream>>>(offA, permA, adj_list + NTRI, r_index + NTRI, scalev,
                                  relAttn + 0 * NREL, rel_emb, out_e, 0);
    k_agg<<<gW, 256, 0, stream>>>(offA, permA, adj_list + NTRI, r_index + NTRI, scalev,
                                  relAttn + 1 * NREL, rel_emb, out_e, 1);
    k_agg<<<gW, 256, 0, stream>>>(offA, permA, adj_list + NTRI, r_index + NTRI, scalev,
                                  relAttn + 2 * NREL, rel_emb, out_r, 0);
    k_agg<<<gW, 256, 0, stream>>>(offA, permA, adj_list + NTRI, r_index + NTRI, scalev,
                                  relAttn + 3 * NREL, rel_emb, out_r, 1);

    dim3 g2(NNODE / 64, F3 / 64);
    // encoder 1 (ent)
    k_rnorm<<<gW, 256, 0, stream>>>(out_e, rnorm);
    k_scores<<<NNODE / 64, 256, 0, stream>>>(out_e, rnorm, pnT_e, pa);
    k_pf<<<g2, 256, 0, stream>>>(pa, e_proxy, out_e, pf);
    k_gate<<<g2, 256, 0, stream>>>(pf, e_gate, e_bias, out_e, out, 0);
    // encoder 2 (rel)
    k_rnorm<<<gW, 256, 0, stream>>>(out_r, rnorm);
    k_scores<<<NNODE / 64, 256, 0, stream>>>(out_r, rnorm, pnT_r, pa);
    k_pf<<<g2, 256, 0, stream>>>(pa, r_proxy, out_r, pf);
    k_gate<<<g2, 256, 0, stream>>>(pf, r_gate, r_bias, out_r, out, 384);
}

// Round 2
// 1292.175 us; speedup vs baseline: 1.3556x; 1.3556x over previous
//
#include <hip/hip_runtime.h>
#include <cmath>

#define NNODE 40000
#define NREL  2000
#define NTRI  600000
#define DIMK  128
#define F3    384
#define NPROX 64
#define EPSN  1e-12f

typedef unsigned short ushort_t;
typedef __attribute__((ext_vector_type(8))) short bf16x8;
typedef __attribute__((ext_vector_type(4))) float f32x4;

static __device__ __forceinline__ float waveSum(float v) {
#pragma unroll
    for (int m = 32; m >= 1; m >>= 1) v += __shfl_xor(v, m, 64);
    return v;
}

static __device__ __forceinline__ float bf2f(ushort_t h) {
    return __uint_as_float(((unsigned int)h) << 16);
}

// ---------------- CSR build (fused over the 3 edge lists) ----------------
__global__ void k_count3(const int* __restrict__ rA, const int* __restrict__ rE,
                         const int* __restrict__ rR, int* __restrict__ dA,
                         int* __restrict__ dE, int* __restrict__ dR) {
    int t = blockIdx.x * 256 + threadIdx.x;
    if (t < NTRI) {
        atomicAdd(&dA[rA[t]], 1);
        atomicAdd(&dE[rE[t]], 1);
        atomicAdd(&dR[rR[t]], 1);
    }
}

// 3 blocks, one per array: thread-serial chunks + shuffle scan (2 barriers total)
__global__ void k_scan_fast(const int* __restrict__ dA, int* __restrict__ oA,
                            const int* __restrict__ dE, int* __restrict__ oE,
                            const int* __restrict__ dR, int* __restrict__ oR) {
    const int* deg = blockIdx.x == 0 ? dA : (blockIdx.x == 1 ? dE : dR);
    int* off = blockIdx.x == 0 ? oA : (blockIdx.x == 1 ? oE : oR);
    __shared__ int wsum[16];
    __shared__ int wpre[16];
    int tid = threadIdx.x;  // 0..1023
    int lane = tid & 63, wv = tid >> 6;
    const int CH = 40;  // 1024*40 >= 40000
    int base = tid * CH;
    int s = 0;
    for (int i = 0; i < CH; i++) {
        int idx = base + i;
        s += (idx < NNODE) ? deg[idx] : 0;
    }
    int incl = s;
#pragma unroll
    for (int m = 1; m < 64; m <<= 1) {
        int v = __shfl_up(incl, m, 64);
        if (lane >= m) incl += v;
    }
    if (lane == 63) wsum[wv] = incl;
    __syncthreads();
    if (tid < 16) {
        int v = wsum[tid];
#pragma unroll
        for (int m = 1; m < 16; m <<= 1) {
            int u = __shfl_up(v, m, 64);
            if (tid >= m) v += u;
        }
        wpre[tid] = v;
    }
    __syncthreads();
    int waveoff = (wv == 0) ? 0 : wpre[wv - 1];
    int run = waveoff + incl - s;  // exclusive prefix of this thread's chunk
    for (int i = 0; i < CH; i++) {
        int idx = base + i;
        if (idx < NNODE) {
            off[idx] = run;
            run += deg[idx];
        }
    }
    if (tid == 0) off[NNODE] = wpre[15];
}

__global__ void k_place3(const int* __restrict__ rA, const int* __restrict__ rE,
                         const int* __restrict__ rR,
                         const int* __restrict__ oA, const int* __restrict__ oE,
                         const int* __restrict__ oR,
                         int* __restrict__ cA, int* __restrict__ cE, int* __restrict__ cR,
                         int* __restrict__ pA, int* __restrict__ pE, int* __restrict__ pR) {
    int t = blockIdx.x * 256 + threadIdx.x;
    if (t < NTRI) {
        int r = rA[t];
        pA[oA[r] + atomicAdd(&cA[r], 1)] = t;
        r = rE[t];
        pE[oE[r] + atomicAdd(&cE[r], 1)] = t;
        r = rR[t];
        pR[oR[r] + atomicAdd(&cR[r], 1)] = t;
    }
}

// ---------------- small precomputes ----------------
// per-relation norm + dots with the 4 attention vectors, packed per layer as float2(e,r)
__global__ void k_relprep(const float* __restrict__ rel_emb,
                          const float* __restrict__ e_attn, const float* __restrict__ r_attn,
                          float* __restrict__ nrm, float2* __restrict__ attL0,
                          float2* __restrict__ attL1) {
    int r = blockIdx.x;
    int lane = threadIdx.x;
    float a = rel_emb[r * DIMK + lane];
    float b = rel_emb[r * DIMK + 64 + lane];
    float nn = waveSum(a * a + b * b);
    float d0 = waveSum(a * e_attn[lane] + b * e_attn[64 + lane]);
    float d1 = waveSum(a * e_attn[DIMK + lane] + b * e_attn[DIMK + 64 + lane]);
    float d2 = waveSum(a * r_attn[lane] + b * r_attn[64 + lane]);
    float d3 = waveSum(a * r_attn[DIMK + lane] + b * r_attn[DIMK + 64 + lane]);
    if (lane == 0) {
        nrm[r] = sqrtf(nn);
        attL0[r] = make_float2(d0, d2);
        attL1[r] = make_float2(d1, d3);
    }
}

__global__ void k_scale(const int* __restrict__ ridx, const float* __restrict__ rval,
                        const float* __restrict__ nrm, float* __restrict__ scalev) {
    int t = blockIdx.x * 256 + threadIdx.x;
    if (t < NTRI) {
        float v = rval[t];
        float nn = fabsf(v) * nrm[ridx[t]];
        scalev[t] = v / fmaxf(nn, EPSN);
    }
}

__global__ void k_proxyprep(const float* __restrict__ proxy, float* __restrict__ pnT) {
    int k = blockIdx.x;      // proxy row 0..63
    int lane = threadIdx.x;  // 0..63
    float v[6];
    float ss = 0.f;
#pragma unroll
    for (int j = 0; j < 6; j++) {
        v[j] = proxy[k * F3 + j * 64 + lane];
        ss += v[j] * v[j];
    }
    ss = waveSum(ss);
    float inv = 1.0f / fmaxf(sqrtf(ss), EPSN);
#pragma unroll
    for (int j = 0; j < 6; j++) pnT[(j * 64 + lane) * NPROX + k] = v[j] * inv;
}

// gate [K=384][N=384] row-major -> transposed bf16 hi/lo [N][K]
__global__ void k_gateprep(const float* __restrict__ g, ushort_t* __restrict__ th,
                           ushort_t* __restrict__ tl) {
    int k = blockIdx.x;      // 0..383
    int c = threadIdx.x;     // 0..383
    float v = g[(size_t)k * F3 + c];
    unsigned int b = __float_as_uint(v);
    th[(size_t)c * F3 + k] = (ushort_t)(b >> 16);
    float lo = v - __uint_as_float(b & 0xffff0000u);
    tl[(size_t)c * F3 + k] = (ushort_t)(__float_as_uint(lo) >> 16);
}

// ---------------- neighbor mean + tanh (writes slice 0) ----------------
__global__ void k_avg_tanh(const int* __restrict__ off, const int* __restrict__ perm,
                           const int* __restrict__ col, const float* __restrict__ emb,
                           float* __restrict__ outb) {
    int wid = (blockIdx.x * blockDim.x + threadIdx.x) >> 6;
    int lane = threadIdx.x & 63;
    if (wid >= NNODE) return;
    int e0 = off[wid], e1 = off[wid + 1];
    const float2* e2 = (const float2*)emb;
    float ax = 0.f, ay = 0.f;
    for (int e = e0; e < e1; e++) {
        int c = col[perm[e]];
        float2 p = e2[(size_t)c * 64 + lane];
        ax += p.x;
        ay += p.y;
    }
    float invd = (e1 > e0) ? 1.0f / (float)(e1 - e0) : 0.0f;
    float2* op = (float2*)(outb + (size_t)wid * F3);
    op[lane] = make_float2(tanhf(ax * invd), tanhf(ay * invd));
}

// ---------------- fused (both encoders) reflection attention aggregation ----------------
__global__ void k_agg2(const int* __restrict__ off, const int* __restrict__ perm,
                       const int* __restrict__ col, const int* __restrict__ ridx,
                       const float* __restrict__ scalev, const float2* __restrict__ attL,
                       const float* __restrict__ rel_emb, float* __restrict__ out_e,
                       float* __restrict__ out_r, int lin) {
    int wid = (blockIdx.x * blockDim.x + threadIdx.x) >> 6;
    int lane = threadIdx.x & 63;
    if (wid >= NNODE) return;
    int e0 = off[wid], e1 = off[wid + 1];
    const float2* rel2 = (const float2*)rel_emb;
    const float2* pe = (const float2*)out_e;
    const float2* pr = (const float2*)out_r;
    int soff = lin * 64 + lane;  // float2 offset of slice `lin` within a row
    float aex = 0.f, aey = 0.f, arx = 0.f, ary = 0.f, sE = 0.f, sR = 0.f;
    for (int e = e0; e < e1; e++) {
        int t = perm[e];
        int c = col[t];
        int r = ridx[t];
        float sc = scalev[t];
        float2 rv = rel2[(size_t)r * 64 + lane];
        float tx = sc * rv.x, ty = sc * rv.y;
        float2 fe = pe[(size_t)c * 192 + soff];
        float2 fr = pr[(size_t)c * 192 + soff];
        float dE = fe.x * tx + fe.y * ty;
        float dR = fr.x * tx + fr.y * ty;
#pragma unroll
        for (int m = 32; m >= 1; m >>= 1) {
            dE += __shfl_xor(dE, m, 64);
            dR += __shfl_xor(dR, m, 64);
        }
        float2 at = attL[r];
        float wE = expf(sc * at.x);
        float wR = expf(sc * at.y);
        aex += wE * (fe.x - 2.f * dE * tx);
        aey += wE * (fe.y - 2.f * dE * ty);
        arx += wR * (fr.x - 2.f * dR * tx);
        ary += wR * (fr.y - 2.f * dR * ty);
        sE += wE;
        sR += wR;
    }
    float iE = (e1 > e0) ? 1.f / sE : 0.f;
    float iR = (e1 > e0) ? 1.f / sR : 0.f;
    float2* oe = (float2*)out_e;
    float2* orr = (float2*)out_r;
    oe[(size_t)wid * 192 + (lin + 1) * 64 + lane] = make_float2(tanhf(aex * iE), tanhf(aey * iE));
    orr[(size_t)wid * 192 + (lin + 1) * 64 + lane] = make_float2(tanhf(arx * iR), tanhf(ary * iR));
}

// ---------------- epilogue ----------------
// scores = l2norm(out) @ proxynT -> softmax -> pa [N][64]; rnorm fused in-loop
__global__ void k_scores(const float* __restrict__ outb, const float* __restrict__ pnT,
                         float* __restrict__ pa) {
    __shared__ __align__(16) float As[16][68];
    __shared__ __align__(16) float Bs[16][68];
    __shared__ float Ss[64][65];
    __shared__ float rnS[64];
    int tid = threadIdx.x;
    int row0 = blockIdx.x * 64;
    int kk = tid & 15, rr = tid >> 4;
    int cb = tid & 63, kb = tid >> 6;
    int tx = tid & 15, ty = tid >> 4;
    int c0 = tx * 4, r0 = ty * 4;
    float acc[4][4] = {};
    float ssp[4] = {};
    for (int k0 = 0; k0 < F3; k0 += 16) {
#pragma unroll
        for (int u = 0; u < 4; u++) {
            int r = rr + u * 16;
            float v = outb[(size_t)(row0 + r) * F3 + k0 + kk];
            As[kk][r] = v;
            ssp[u] += v * v;
        }
#pragma unroll
        for (int u = 0; u < 4; u++) {
            int k = kb + u * 4;
            Bs[k][cb] = pnT[(size_t)(k0 + k) * NPROX + cb];
        }
        __syncthreads();
#pragma unroll
        for (int k = 0; k < 16; k++) {
            float4 av = *(const float4*)&As[k][r0];
            float4 bv = *(const float4*)&Bs[k][c0];
            float a[4] = {av.x, av.y, av.z, av.w};
            float b[4] = {bv.x, bv.y, bv.z, bv.w};
#pragma unroll
            for (int i = 0; i < 4; i++)
#pragma unroll
                for (int j = 0; j < 4; j++) acc[i][j] += a[i] * b[j];
        }
        __syncthreads();
    }
    // reduce row sum-squares over the 16 kk lanes (same wave)
#pragma unroll
    for (int u = 0; u < 4; u++) {
        float ss = ssp[u];
#pragma unroll
        for (int m = 1; m < 16; m <<= 1) ss += __shfl_xor(ss, m, 64);
        if (kk == 0) rnS[rr + u * 16] = 1.0f / fmaxf(sqrtf(ss), EPSN);
    }
    __syncthreads();
#pragma unroll
    for (int i = 0; i < 4; i++) {
        float rn = rnS[r0 + i];
#pragma unroll
        for (int j = 0; j < 4; j++) Ss[r0 + i][c0 + j] = acc[i][j] * rn;
    }
    __syncthreads();
    if (tid < 64) {
        int r = tid;
        float m = -1e30f;
        for (int c = 0; c < 64; c++) m = fmaxf(m, Ss[r][c]);
        float s = 0.f;
        for (int c = 0; c < 64; c++) s += expf(Ss[r][c] - m);
        float inv = 1.f / s;
        float* po = pa + (size_t)(row0 + r) * NPROX;
        for (int c = 0; c < 64; c++) po[c] = expf(Ss[r][c] - m) * inv;
    }
}

// pf = out - pa @ proxy, stored as bf16 hi/lo pair
__global__ void k_pf(const float* __restrict__ pa, const float* __restrict__ proxy,
                     const float* __restrict__ outb, ushort_t* __restrict__ pfh,
                     ushort_t* __restrict__ pfl) {
    __shared__ __align__(16) float As[16][68];
    __shared__ __align__(16) float Bs[16][68];
    int tid = threadIdx.x;
    int row0 = blockIdx.x * 64;
    int col0 = blockIdx.y * 64;
    int kk = tid & 15, rr = tid >> 4;
    int cb = tid & 63, kb = tid >> 6;
    int tx = tid & 15, ty = tid >> 4;
    int c0 = tx * 4, r0 = ty * 4;
    float acc[4][4] = {};
    for (int k0 = 0; k0 < NPROX; k0 += 16) {
#pragma unroll
        for (int u = 0; u < 4; u++) {
            int r = rr + u * 16;
            As[kk][r] = pa[(size_t)(row0 + r) * NPROX + k0 + kk];
        }
#pragma unroll
        for (int u = 0; u < 4; u++) {
            int k = kb + u * 4;
            Bs[k][cb] = proxy[(size_t)(k0 + k) * F3 + col0 + cb];
        }
        __syncthreads();
#pragma unroll
        for (int k = 0; k < 16; k++) {
            float4 av = *(const float4*)&As[k][r0];
            float4 bv = *(const float4*)&Bs[k][c0];
            float a[4] = {av.x, av.y, av.z, av.w};
            float b[4] = {bv.x, bv.y, bv.z, bv.w};
#pragma unroll
            for (int i = 0; i < 4; i++)
#pragma unroll
                for (int j = 0; j < 4; j++) acc[i][j] += a[i] * b[j];
        }
        __syncthreads();
    }
#pragma unroll
    for (int i = 0; i < 4; i++)
#pragma unroll
        for (int j = 0; j < 4; j++) {
            size_t idx = (size_t)(row0 + r0 + i) * F3 + col0 + c0 + j;
            float v = outb[idx] - acc[i][j];
            unsigned int b = __float_as_uint(v);
            pfh[idx] = (ushort_t)(b >> 16);
            float lo = v - __uint_as_float(b & 0xffff0000u);
            pfl[idx] = (ushort_t)(__float_as_uint(lo) >> 16);
        }
}

// gate GEMM via bf16 hi/lo split MFMA; fused sigmoid + blend + store to d_out slice
__global__ __launch_bounds__(256) void k_gate_mfma(
    const ushort_t* __restrict__ pfh, const ushort_t* __restrict__ pfl,
    const ushort_t* __restrict__ gTh, const ushort_t* __restrict__ gTl,
    const float* __restrict__ bias, const float* __restrict__ outb,
    float* __restrict__ dout, int outoff) {
    __shared__ __align__(16) ushort_t AsH[128 * 40];
    __shared__ __align__(16) ushort_t AsL[128 * 40];
    int tid = threadIdx.x;
    int w = tid >> 6, lane = tid & 63;
    int quad = lane >> 4, l16 = lane & 15;
    int wrow = (w >> 1) * 64, wcol = (w & 1) * 64;
    int gr0 = blockIdx.x * 128;
    int cb0 = blockIdx.y * 128;
    f32x4 acc[4][4];
#pragma unroll
    for (int rt = 0; rt < 4; rt++)
#pragma unroll
        for (int ct = 0; ct < 4; ct++) acc[rt][ct] = (f32x4){0.f, 0.f, 0.f, 0.f};

    int srow = tid >> 2, sseg = tid & 3;
    for (int k0 = 0; k0 < F3; k0 += 32) {
        __syncthreads();
#pragma unroll
        for (int u = 0; u < 2; u++) {
            int row = srow + u * 64;
            int gr = gr0 + row;
            uint4 vh = {0, 0, 0, 0}, vl = {0, 0, 0, 0};
            if (gr < NNODE) {
                vh = *(const uint4*)&pfh[(size_t)gr * F3 + k0 + sseg * 8];
                vl = *(const uint4*)&pfl[(size_t)gr * F3 + k0 + sseg * 8];
            }
            *(uint4*)&AsH[row * 40 + sseg * 8] = vh;
            *(uint4*)&AsL[row * 40 + sseg * 8] = vl;
        }
        __syncthreads();
        bf16x8 ah[4], al[4], bh[4], bl[4];
#pragma unroll
        for (int rt = 0; rt < 4; rt++) {
            int ar = wrow + rt * 16 + l16;
            ah[rt] = *(const bf16x8*)&AsH[ar * 40 + quad * 8];
            al[rt] = *(const bf16x8*)&AsL[ar * 40 + quad * 8];
        }
#pragma unroll
        for (int ct = 0; ct < 4; ct++) {
            int bc = cb0 + wcol + ct * 16 + l16;
            bh[ct] = *(const bf16x8*)&gTh[(size_t)bc * F3 + k0 + quad * 8];
            bl[ct] = *(const bf16x8*)&gTl[(size_t)bc * F3 + k0 + quad * 8];
        }
#pragma unroll
        for (int rt = 0; rt < 4; rt++)
#pragma unroll
            for (int ct = 0; ct < 4; ct++) {
                acc[rt][ct] = __builtin_amdgcn_mfma_f32_16x16x32_bf16(ah[rt], bh[ct], acc[rt][ct], 0, 0, 0);
                acc[rt][ct] = __builtin_amdgcn_mfma_f32_16x16x32_bf16(ah[rt], bl[ct], acc[rt][ct], 0, 0, 0);
                acc[rt][ct] = __builtin_amdgcn_mfma_f32_16x16x32_bf16(al[rt], bh[ct], acc[rt][ct], 0, 0, 0);
            }
    }
    // epilogue: C/D layout col=lane&15, row=quad*4+reg (m89-verified)
#pragma unroll
    for (int rt = 0; rt < 4; rt++) {
        int rbase = gr0 + wrow + rt * 16 + quad * 4;
#pragma unroll
        for (int reg = 0; reg < 4; reg++) {
            int row = rbase + reg;
            if (row >= NNODE) continue;
#pragma unroll
            for (int ct = 0; ct < 4; ct++) {
                int c = cb0 + wcol + ct * 16 + l16;
                float x = acc[rt][ct][reg] + bias[c];
                float g = 1.f / (1.f + __expf(-x));
                size_t idx = (size_t)row * F3 + c;
                float pf = bf2f(pfh[idx]) + bf2f(pfl[idx]);
                float o = outb[idx];
                dout[(size_t)row * 768 + outoff + c] = g * o + (1.f - g) * pf;
            }
        }
    }
}

// ---------------- launch ----------------
extern "C" void kernel_launch(void* const* d_in, const int* in_sizes, int n_in,
                              void* d_out, int out_size, void* d_ws, size_t ws_size,
                              hipStream_t stream) {
    const int* ent_adj = (const int*)d_in[0];
    const int* rel_adj = (const int*)d_in[1];
    const int* adj_list = (const int*)d_in[4];
    const int* r_index = (const int*)d_in[5];
    const float* r_val = (const float*)d_in[6];
    const float* ent_emb = (const float*)d_in[9];
    const float* rel_emb = (const float*)d_in[10];
    const float* e_attn = (const float*)d_in[11];
    const float* e_gate = (const float*)d_in[12];
    const float* e_proxy = (const float*)d_in[13];
    const float* e_bias = (const float*)d_in[14];
    const float* r_attn = (const float*)d_in[15];
    const float* r_gate = (const float*)d_in[16];
    const float* r_proxy = (const float*)d_in[17];
    const float* r_bias = (const float*)d_in[18];
    float* out = (float*)d_out;

    char* ws = (char*)d_ws;
    size_t off = 0;
    auto alloc = [&](size_t bytes) -> void* {
        off = (off + 255) & ~(size_t)255;
        void* p = ws + off;
        off += bytes;
        return p;
    };

    int* degcur = (int*)alloc(6 * NNODE * sizeof(int));
    int* degA = degcur, *curA = degcur + NNODE;
    int* degE = degcur + 2 * NNODE, *curE = degcur + 3 * NNODE;
    int* degR = degcur + 4 * NNODE, *curR = degcur + 5 * NNODE;
    int* offA = (int*)alloc((NNODE + 1) * sizeof(int));
    int* offE = (int*)alloc((NNODE + 1) * sizeof(int));
    int* offR = (int*)alloc((NNODE + 1) * sizeof(int));
    int* permA = (int*)alloc(NTRI * sizeof(int));
    int* permE = (int*)alloc(NTRI * sizeof(int));
    int* permR = (int*)alloc(NTRI * sizeof(int));
    float* nrm = (float*)alloc(NREL * sizeof(float));
    float2* attL0 = (float2*)alloc(NREL * sizeof(float2));
    float2* attL1 = (float2*)alloc(NREL * sizeof(float2));
    float* scalev = (float*)alloc(NTRI * sizeof(float));
    float* pnT = (float*)alloc((size_t)F3 * NPROX * sizeof(float));
    ushort_t* gTh = (ushort_t*)alloc((size_t)F3 * F3 * sizeof(ushort_t));
    ushort_t* gTl = (ushort_t*)alloc((size_t)F3 * F3 * sizeof(ushort_t));
    float* pa = (float*)alloc((size_t)NNODE * NPROX * sizeof(float));
    ushort_t* pfh = (ushort_t*)alloc((size_t)NNODE * F3 * sizeof(ushort_t));
    ushort_t* pfl = (ushort_t*)alloc((size_t)NNODE * F3 * sizeof(ushort_t));
    float* out_e = (float*)alloc((size_t)NNODE * F3 * sizeof(float));
    float* out_r = (float*)alloc((size_t)NNODE * F3 * sizeof(float));
    (void)ws_size; (void)in_sizes; (void)n_in; (void)out_size;

    hipMemsetAsync(degcur, 0, 6 * NNODE * sizeof(int), stream);

    int gT = (NTRI + 255) / 256;
    k_count3<<<gT, 256, 0, stream>>>(adj_list, ent_adj, rel_adj, degA, degE, degR);
    k_scan_fast<<<3, 1024, 0, stream>>>(degA, offA, degE, offE, degR, offR);
    k_place3<<<gT, 256, 0, stream>>>(adj_list, ent_adj, rel_adj, offA, offE, offR,
                                     curA, curE, curR, permA, permE, permR);

    k_relprep<<<NREL, 64, 0, stream>>>(rel_emb, e_attn, r_attn, nrm, attL0, attL1);
    k_scale<<<gT, 256, 0, stream>>>(r_index + NTRI, r_val, nrm, scalev);

    int gW = NNODE / 4;  // 4 waves (rows) per 256-thread block
    k_avg_tanh<<<gW, 256, 0, stream>>>(offE, permE, ent_adj + NTRI, ent_emb, out_e);
    k_avg_tanh<<<gW, 256, 0, stream>>>(offR, permR, rel_adj + NTRI, rel_emb, out_r);

    k_agg2<<<gW, 256, 0, stream>>>(offA, permA, adj_list + NTRI, r_index + NTRI, scalev,
                                   attL0, rel_emb, out_e, out_r, 0);
    k_agg2<<<gW, 256, 0, stream>>>(offA, permA, adj_list + NTRI, r_index + NTRI, scalev,
                                   attL1, rel_emb, out_e, out_r, 1);

    dim3 g2(NNODE / 64, F3 / 64);
    dim3 g3((NNODE + 127) / 128, F3 / 128);
    // encoder 1 (ent)
    k_proxyprep<<<NPROX, 64, 0, stream>>>(e_proxy, pnT);
    k_gateprep<<<F3, F3, 0, stream>>>(e_gate, gTh, gTl);
    k_scores<<<NNODE / 64, 256, 0, stream>>>(out_e, pnT, pa);
    k_pf<<<g2, 256, 0, stream>>>(pa, e_proxy, out_e, pfh, pfl);
    k_gate_mfma<<<g3, 256, 0, stream>>>(pfh, pfl, gTh, gTl, e_bias, out_e, out, 0);
    // encoder 2 (rel)
    k_proxyprep<<<NPROX, 64, 0, stream>>>(r_proxy, pnT);
    k_gateprep<<<F3, F3, 0, stream>>>(r_gate, gTh, gTl);
    k_scores<<<NNODE / 64, 256, 0, stream>>>(out_r, pnT, pa);
    k_pf<<<g2, 256, 0, stream>>>(pa, r_proxy, out_r, pfh, pfl);
    k_gate_mfma<<<g3, 256, 0, stream>>>(pfh, pfl, gTh, gTl, r_bias, out_r, out, 384);
}

// Round 3
// 1058.530 us; speedup vs baseline: 1.6548x; 1.2207x over previous
//
#include <hip/hip_runtime.h>
#include <cmath>

#define NNODE 40000
#define NREL  2000
#define NTRI  600000
#define DIMK  128
#define F3    384
#define NPROX 64
#define EPSN  1e-12f

typedef unsigned short ushort_t;
typedef __attribute__((ext_vector_type(8))) short bf16x8;
typedef __attribute__((ext_vector_type(4))) float f32x4;

static __device__ __forceinline__ float waveSum(float v) {
#pragma unroll
    for (int m = 32; m >= 1; m >>= 1) v += __shfl_xor(v, m, 64);
    return v;
}

static __device__ __forceinline__ float bf2f(ushort_t h) {
    return __uint_as_float(((unsigned int)h) << 16);
}

static __device__ __forceinline__ void qreduce4(float4& v) {
    // sum across the 4 quarters (lanes ^16, ^32)
#pragma unroll
    for (int m = 16; m <= 32; m <<= 1) {
        v.x += __shfl_xor(v.x, m, 64);
        v.y += __shfl_xor(v.y, m, 64);
        v.z += __shfl_xor(v.z, m, 64);
        v.w += __shfl_xor(v.w, m, 64);
    }
}

// ---------------- CSR build (fused over the 3 edge lists) ----------------
__global__ void k_count3(const int* __restrict__ rA, const int* __restrict__ rE,
                         const int* __restrict__ rR, int* __restrict__ dA,
                         int* __restrict__ dE, int* __restrict__ dR) {
    int t = blockIdx.x * 256 + threadIdx.x;
    if (t < NTRI) {
        atomicAdd(&dA[rA[t]], 1);
        atomicAdd(&dE[rE[t]], 1);
        atomicAdd(&dR[rR[t]], 1);
    }
}

// 3 blocks, one per array: thread-serial chunks + shuffle scan
__global__ void k_scan_fast(const int* __restrict__ dA, int* __restrict__ oA,
                            const int* __restrict__ dE, int* __restrict__ oE,
                            const int* __restrict__ dR, int* __restrict__ oR) {
    const int* deg = blockIdx.x == 0 ? dA : (blockIdx.x == 1 ? dE : dR);
    int* off = blockIdx.x == 0 ? oA : (blockIdx.x == 1 ? oE : oR);
    __shared__ int wsum[16];
    __shared__ int wpre[16];
    int tid = threadIdx.x;  // 0..1023
    int lane = tid & 63, wv = tid >> 6;
    const int CH = 40;
    int base = tid * CH;
    int s = 0;
    for (int i = 0; i < CH; i++) {
        int idx = base + i;
        s += (idx < NNODE) ? deg[idx] : 0;
    }
    int incl = s;
#pragma unroll
    for (int m = 1; m < 64; m <<= 1) {
        int v = __shfl_up(incl, m, 64);
        if (lane >= m) incl += v;
    }
    if (lane == 63) wsum[wv] = incl;
    __syncthreads();
    if (tid < 16) {
        int v = wsum[tid];
#pragma unroll
        for (int m = 1; m < 16; m <<= 1) {
            int u = __shfl_up(v, m, 64);
            if (tid >= m) v += u;
        }
        wpre[tid] = v;
    }
    __syncthreads();
    int waveoff = (wv == 0) ? 0 : wpre[wv - 1];
    int run = waveoff + incl - s;
    for (int i = 0; i < CH; i++) {
        int idx = base + i;
        if (idx < NNODE) {
            off[idx] = run;
            run += deg[idx];
        }
    }
    if (tid == 0) off[NNODE] = wpre[15];
}

// place edge PAYLOADS at sorted positions (no perm indirection downstream)
__global__ void k_place3(const int* __restrict__ rA, const int* __restrict__ cA,
                         const int* __restrict__ rE, const int* __restrict__ cE,
                         const int* __restrict__ rR, const int* __restrict__ cR,
                         const int* __restrict__ ridx, const float* __restrict__ scalev,
                         const int* __restrict__ oA, const int* __restrict__ oE,
                         const int* __restrict__ oR,
                         int* __restrict__ cntA, int* __restrict__ cntE, int* __restrict__ cntR,
                         int* __restrict__ ePack, float* __restrict__ eSc,
                         int* __restrict__ eColE, int* __restrict__ eColR) {
    int t = blockIdx.x * 256 + threadIdx.x;
    if (t < NTRI) {
        int r = rA[t];
        int p = oA[r] + atomicAdd(&cntA[r], 1);
        ePack[p] = cA[t] | (ridx[t] << 16);  // col<65536, rid<2000
        eSc[p] = scalev[t];
        r = rE[t];
        eColE[oE[r] + atomicAdd(&cntE[r], 1)] = cE[t];
        r = rR[t];
        eColR[oR[r] + atomicAdd(&cntR[r], 1)] = cR[t];
    }
}

// ---------------- small precomputes ----------------
__global__ void k_relprep(const float* __restrict__ rel_emb,
                          const float* __restrict__ e_attn, const float* __restrict__ r_attn,
                          float* __restrict__ nrm, float2* __restrict__ attL0,
                          float2* __restrict__ attL1) {
    int r = blockIdx.x;
    int lane = threadIdx.x;
    float a = rel_emb[r * DIMK + lane];
    float b = rel_emb[r * DIMK + 64 + lane];
    float nn = waveSum(a * a + b * b);
    float d0 = waveSum(a * e_attn[lane] + b * e_attn[64 + lane]);
    float d1 = waveSum(a * e_attn[DIMK + lane] + b * e_attn[DIMK + 64 + lane]);
    float d2 = waveSum(a * r_attn[lane] + b * r_attn[64 + lane]);
    float d3 = waveSum(a * r_attn[DIMK + lane] + b * r_attn[DIMK + 64 + lane]);
    if (lane == 0) {
        nrm[r] = sqrtf(nn);
        attL0[r] = make_float2(d0, d2);
        attL1[r] = make_float2(d1, d3);
    }
}

__global__ void k_scale(const int* __restrict__ ridx, const float* __restrict__ rval,
                        const float* __restrict__ nrm, float* __restrict__ scalev) {
    int t = blockIdx.x * 256 + threadIdx.x;
    if (t < NTRI) {
        float v = rval[t];
        float nn = fabsf(v) * nrm[ridx[t]];
        scalev[t] = v / fmaxf(nn, EPSN);
    }
}

__global__ void k_proxyprep(const float* __restrict__ proxy, float* __restrict__ pnT) {
    int k = blockIdx.x;
    int lane = threadIdx.x;
    float v[6];
    float ss = 0.f;
#pragma unroll
    for (int j = 0; j < 6; j++) {
        v[j] = proxy[k * F3 + j * 64 + lane];
        ss += v[j] * v[j];
    }
    ss = waveSum(ss);
    float inv = 1.0f / fmaxf(sqrtf(ss), EPSN);
#pragma unroll
    for (int j = 0; j < 6; j++) pnT[(j * 64 + lane) * NPROX + k] = v[j] * inv;
}

__global__ void k_gateprep(const float* __restrict__ g, ushort_t* __restrict__ th,
                           ushort_t* __restrict__ tl) {
    int k = blockIdx.x;
    int c = threadIdx.x;
    float v = g[(size_t)k * F3 + c];
    unsigned int b = __float_as_uint(v);
    th[(size_t)c * F3 + k] = (ushort_t)(b >> 16);
    float lo = v - __uint_as_float(b & 0xffff0000u);
    tl[(size_t)c * F3 + k] = (ushort_t)(__float_as_uint(lo) >> 16);
}

// ---------------- fused neighbor mean + tanh (both encoders, quarter-wave) ----------------
__global__ __launch_bounds__(256) void k_avg2(
    const int* __restrict__ offE, const int* __restrict__ eColE, const float* __restrict__ ent_emb,
    const int* __restrict__ offR, const int* __restrict__ eColR, const float* __restrict__ rel_emb,
    float* __restrict__ out_e, float* __restrict__ out_r) {
    int gw = (blockIdx.x * blockDim.x + threadIdx.x) >> 6;
    int lane = threadIdx.x & 63;
    if (gw >= 2 * NNODE) return;
    bool isR = gw >= NNODE;
    int wid = isR ? gw - NNODE : gw;
    const int* off = isR ? offR : offE;
    const int* ecol = isR ? eColR : eColE;
    const float4* emb4 = (const float4*)(isR ? rel_emb : ent_emb);
    float* outp = isR ? out_r : out_e;
    int q = lane >> 4, ql = lane & 15;
    int e0 = off[wid], e1 = off[wid + 1];
    float4 aA = {0, 0, 0, 0}, aB = {0, 0, 0, 0};
    for (int base = e0; base < e1; base += 64) {
        int n = min(64, e1 - base);
        int mc = (lane < n) ? ecol[base + lane] : -1;
        for (int j = 0; j < n; j += 4) {
            int e = j + q;
            int c = __shfl(mc, e, 64);
            if (e < n) {
                float4 va = emb4[(size_t)c * 32 + ql];
                float4 vb = emb4[(size_t)c * 32 + 16 + ql];
                aA.x += va.x; aA.y += va.y; aA.z += va.z; aA.w += va.w;
                aB.x += vb.x; aB.y += vb.y; aB.z += vb.z; aB.w += vb.w;
            }
        }
    }
    qreduce4(aA);
    qreduce4(aB);
    if (q == 0) {
        float invd = (e1 > e0) ? 1.0f / (float)(e1 - e0) : 0.0f;
        float4* o = (float4*)outp;
        float4 ra = {tanhf(aA.x * invd), tanhf(aA.y * invd), tanhf(aA.z * invd), tanhf(aA.w * invd)};
        float4 rb = {tanhf(aB.x * invd), tanhf(aB.y * invd), tanhf(aB.z * invd), tanhf(aB.w * invd)};
        o[(size_t)wid * 96 + ql] = ra;
        o[(size_t)wid * 96 + 16 + ql] = rb;
    }
}

// ---------------- fused reflection attention aggregation (quarter-wave, 4 edges in flight) ----
__global__ __launch_bounds__(256) void k_agg2(
    const int* __restrict__ off, const int* __restrict__ ePack, const float* __restrict__ eSc,
    const float2* __restrict__ attL, const float* __restrict__ rel_emb,
    float* __restrict__ out_e, float* __restrict__ out_r, int lin) {
    int wid = (blockIdx.x * blockDim.x + threadIdx.x) >> 6;
    int lane = threadIdx.x & 63;
    if (wid >= NNODE) return;
    int q = lane >> 4, ql = lane & 15;
    int e0 = off[wid], e1 = off[wid + 1];
    const float4* rel4 = (const float4*)rel_emb;
    const float4* pe4 = (const float4*)out_e;
    const float4* pr4 = (const float4*)out_r;
    int sA = lin * 32 + ql, sB = lin * 32 + 16 + ql;
    float4 aEa = {0, 0, 0, 0}, aEb = {0, 0, 0, 0}, aRa = {0, 0, 0, 0}, aRb = {0, 0, 0, 0};
    float sE = 0.f, sR = 0.f;
    for (int base = e0; base < e1; base += 64) {
        int n = min(64, e1 - base);
        int pk = 0;
        float sc = 0.f, wE = 0.f, wR = 0.f;
        if (lane < n) {
            pk = ePack[base + lane];
            sc = eSc[base + lane];
            float2 a = attL[pk >> 16];
            wE = __expf(sc * a.x);
            wR = __expf(sc * a.y);
        }
        for (int j = 0; j < n; j += 4) {
            int e = j + q;
            int pke = __shfl(pk, e, 64);
            float sce = __shfl(sc, e, 64);
            float wEe = __shfl(wE, e, 64);
            float wRe = __shfl(wR, e, 64);
            int c = pke & 0xFFFF;
            int r = pke >> 16;
            float4 ra = rel4[(size_t)r * 32 + ql];
            float4 rb = rel4[(size_t)r * 32 + 16 + ql];
            float4 fa = pe4[(size_t)c * 96 + sA];
            float4 fb = pe4[(size_t)c * 96 + sB];
            float4 ga = pr4[(size_t)c * 96 + sA];
            float4 gb = pr4[(size_t)c * 96 + sB];
            float tax = sce * ra.x, tay = sce * ra.y, taz = sce * ra.z, taw = sce * ra.w;
            float tbx = sce * rb.x, tby = sce * rb.y, tbz = sce * rb.z, tbw = sce * rb.w;
            float dE = fa.x * tax + fa.y * tay + fa.z * taz + fa.w * taw +
                       fb.x * tbx + fb.y * tby + fb.z * tbz + fb.w * tbw;
            float dR = ga.x * tax + ga.y * tay + ga.z * taz + ga.w * taw +
                       gb.x * tbx + gb.y * tby + gb.z * tbz + gb.w * tbw;
#pragma unroll
            for (int m = 1; m <= 8; m <<= 1) {
                dE += __shfl_xor(dE, m, 64);
                dR += __shfl_xor(dR, m, 64);
            }
            dE *= 2.f;
            dR *= 2.f;
            aEa.x += wEe * (fa.x - dE * tax);
            aEa.y += wEe * (fa.y - dE * tay);
            aEa.z += wEe * (fa.z - dE * taz);
            aEa.w += wEe * (fa.w - dE * taw);
            aEb.x += wEe * (fb.x - dE * tbx);
            aEb.y += wEe * (fb.y - dE * tby);
            aEb.z += wEe * (fb.z - dE * tbz);
            aEb.w += wEe * (fb.w - dE * tbw);
            aRa.x += wRe * (ga.x - dR * tax);
            aRa.y += wRe * (ga.y - dR * tay);
            aRa.z += wRe * (ga.z - dR * taz);
            aRa.w += wRe * (ga.w - dR * taw);
            aRb.x += wRe * (gb.x - dR * tbx);
            aRb.y += wRe * (gb.y - dR * tby);
            aRb.z += wRe * (gb.z - dR * tbz);
            aRb.w += wRe * (gb.w - dR * tbw);
            sE += wEe;
            sR += wRe;
        }
    }
    qreduce4(aEa);
    qreduce4(aEb);
    qreduce4(aRa);
    qreduce4(aRb);
#pragma unroll
    for (int m = 16; m <= 32; m <<= 1) {
        sE += __shfl_xor(sE, m, 64);
        sR += __shfl_xor(sR, m, 64);
    }
    if (q == 0) {
        float iE = (e1 > e0) ? 1.f / sE : 0.f;
        float4* o = (float4*)out_e;
        float4 wa = {tanhf(aEa.x * iE), tanhf(aEa.y * iE), tanhf(aEa.z * iE), tanhf(aEa.w * iE)};
        float4 wb = {tanhf(aEb.x * iE), tanhf(aEb.y * iE), tanhf(aEb.z * iE), tanhf(aEb.w * iE)};
        o[(size_t)wid * 96 + (lin + 1) * 32 + ql] = wa;
        o[(size_t)wid * 96 + (lin + 1) * 32 + 16 + ql] = wb;
    } else if (q == 1) {
        float iR = (e1 > e0) ? 1.f / sR : 0.f;
        float4* o = (float4*)out_r;
        float4 wa = {tanhf(aRa.x * iR), tanhf(aRa.y * iR), tanhf(aRa.z * iR), tanhf(aRa.w * iR)};
        float4 wb = {tanhf(aRb.x * iR), tanhf(aRb.y * iR), tanhf(aRb.z * iR), tanhf(aRb.w * iR)};
        o[(size_t)wid * 96 + (lin + 1) * 32 + ql] = wa;
        o[(size_t)wid * 96 + (lin + 1) * 32 + 16 + ql] = wb;
    }
}

// ---------------- epilogue ----------------
__global__ void k_scores(const float* __restrict__ outb, const float* __restrict__ pnT,
                         float* __restrict__ pa) {
    __shared__ __align__(16) float As[16][68];
    __shared__ __align__(16) float Bs[16][68];
    __shared__ float Ss[64][65];
    __shared__ float rnS[64];
    int tid = threadIdx.x;
    int row0 = blockIdx.x * 64;
    int kk = tid & 15, rr = tid >> 4;
    int cb = tid & 63, kb = tid >> 6;
    int tx = tid & 15, ty = tid >> 4;
    int c0 = tx * 4, r0 = ty * 4;
    float acc[4][4] = {};
    float ssp[4] = {};
    for (int k0 = 0; k0 < F3; k0 += 16) {
#pragma unroll
        for (int u = 0; u < 4; u++) {
            int r = rr + u * 16;
            float v = outb[(size_t)(row0 + r) * F3 + k0 + kk];
            As[kk][r] = v;
            ssp[u] += v * v;
        }
#pragma unroll
        for (int u = 0; u < 4; u++) {
            int k = kb + u * 4;
            Bs[k][cb] = pnT[(size_t)(k0 + k) * NPROX + cb];
        }
        __syncthreads();
#pragma unroll
        for (int k = 0; k < 16; k++) {
            float4 av = *(const float4*)&As[k][r0];
            float4 bv = *(const float4*)&Bs[k][c0];
            float a[4] = {av.x, av.y, av.z, av.w};
            float b[4] = {bv.x, bv.y, bv.z, bv.w};
#pragma unroll
            for (int i = 0; i < 4; i++)
#pragma unroll
                for (int j = 0; j < 4; j++) acc[i][j] += a[i] * b[j];
        }
        __syncthreads();
    }
#pragma unroll
    for (int u = 0; u < 4; u++) {
        float ss = ssp[u];
#pragma unroll
        for (int m = 1; m < 16; m <<= 1) ss += __shfl_xor(ss, m, 64);
        if (kk == 0) rnS[rr + u * 16] = 1.0f / fmaxf(sqrtf(ss), EPSN);
    }
    __syncthreads();
#pragma unroll
    for (int i = 0; i < 4; i++) {
        float rn = rnS[r0 + i];
#pragma unroll
        for (int j = 0; j < 4; j++) Ss[r0 + i][c0 + j] = acc[i][j] * rn;
    }
    __syncthreads();
    if (tid < 64) {
        int r = tid;
        float m = -1e30f;
        for (int c = 0; c < 64; c++) m = fmaxf(m, Ss[r][c]);
        float s = 0.f;
        for (int c = 0; c < 64; c++) s += expf(Ss[r][c] - m);
        float inv = 1.f / s;
        float* po = pa + (size_t)(row0 + r) * NPROX;
        for (int c = 0; c < 64; c++) po[c] = expf(Ss[r][c] - m) * inv;
    }
}

__global__ void k_pf(const float* __restrict__ pa, const float* __restrict__ proxy,
                     const float* __restrict__ outb, ushort_t* __restrict__ pfh,
                     ushort_t* __restrict__ pfl) {
    __shared__ __align__(16) float As[16][68];
    __shared__ __align__(16) float Bs[16][68];
    int tid = threadIdx.x;
    int row0 = blockIdx.x * 64;
    int col0 = blockIdx.y * 64;
    int kk = tid & 15, rr = tid >> 4;
    int cb = tid & 63, kb = tid >> 6;
    int tx = tid & 15, ty = tid >> 4;
    int c0 = tx * 4, r0 = ty * 4;
    float acc[4][4] = {};
    for (int k0 = 0; k0 < NPROX; k0 += 16) {
#pragma unroll
        for (int u = 0; u < 4; u++) {
            int r = rr + u * 16;
            As[kk][r] = pa[(size_t)(row0 + r) * NPROX + k0 + kk];
        }
#pragma unroll
        for (int u = 0; u < 4; u++) {
            int k = kb + u * 4;
            Bs[k][cb] = proxy[(size_t)(k0 + k) * F3 + col0 + cb];
        }
        __syncthreads();
#pragma unroll
        for (int k = 0; k < 16; k++) {
            float4 av = *(const float4*)&As[k][r0];
            float4 bv = *(const float4*)&Bs[k][c0];
            float a[4] = {av.x, av.y, av.z, av.w};
            float b[4] = {bv.x, bv.y, bv.z, bv.w};
#pragma unroll
            for (int i = 0; i < 4; i++)
#pragma unroll
                for (int j = 0; j < 4; j++) acc[i][j] += a[i] * b[j];
        }
        __syncthreads();
    }
#pragma unroll
    for (int i = 0; i < 4; i++)
#pragma unroll
        for (int j = 0; j < 4; j++) {
            size_t idx = (size_t)(row0 + r0 + i) * F3 + col0 + c0 + j;
            float v = outb[idx] - acc[i][j];
            unsigned int b = __float_as_uint(v);
            pfh[idx] = (ushort_t)(b >> 16);
            float lo = v - __uint_as_float(b & 0xffff0000u);
            pfl[idx] = (ushort_t)(__float_as_uint(lo) >> 16);
        }
}

__global__ __launch_bounds__(256) void k_gate_mfma(
    const ushort_t* __restrict__ pfh, const ushort_t* __restrict__ pfl,
    const ushort_t* __restrict__ gTh, const ushort_t* __restrict__ gTl,
    const float* __restrict__ bias, const float* __restrict__ outb,
    float* __restrict__ dout, int outoff) {
    __shared__ __align__(16) ushort_t AsH[128 * 40];
    __shared__ __align__(16) ushort_t AsL[128 * 40];
    int tid = threadIdx.x;
    int w = tid >> 6, lane = tid & 63;
    int quad = lane >> 4, l16 = lane & 15;
    int wrow = (w >> 1) * 64, wcol = (w & 1) * 64;
    int gr0 = blockIdx.x * 128;
    int cb0 = blockIdx.y * 128;
    f32x4 acc[4][4];
#pragma unroll
    for (int rt = 0; rt < 4; rt++)
#pragma unroll
        for (int ct = 0; ct < 4; ct++) acc[rt][ct] = (f32x4){0.f, 0.f, 0.f, 0.f};

    int srow = tid >> 2, sseg = tid & 3;
    for (int k0 = 0; k0 < F3; k0 += 32) {
        __syncthreads();
#pragma unroll
        for (int u = 0; u < 2; u++) {
            int row = srow + u * 64;
            int gr = gr0 + row;
            uint4 vh = {0, 0, 0, 0}, vl = {0, 0, 0, 0};
            if (gr < NNODE) {
                vh = *(const uint4*)&pfh[(size_t)gr * F3 + k0 + sseg * 8];
                vl = *(const uint4*)&pfl[(size_t)gr * F3 + k0 + sseg * 8];
            }
            *(uint4*)&AsH[row * 40 + sseg * 8] = vh;
            *(uint4*)&AsL[row * 40 + sseg * 8] = vl;
        }
        __syncthreads();
        bf16x8 ah[4], al[4], bh[4], bl[4];
#pragma unroll
        for (int rt = 0; rt < 4; rt++) {
            int ar = wrow + rt * 16 + l16;
            ah[rt] = *(const bf16x8*)&AsH[ar * 40 + quad * 8];
            al[rt] = *(const bf16x8*)&AsL[ar * 40 + quad * 8];
        }
#pragma unroll
        for (int ct = 0; ct < 4; ct++) {
            int bc = cb0 + wcol + ct * 16 + l16;
            bh[ct] = *(const bf16x8*)&gTh[(size_t)bc * F3 + k0 + quad * 8];
            bl[ct] = *(const bf16x8*)&gTl[(size_t)bc * F3 + k0 + quad * 8];
        }
#pragma unroll
        for (int rt = 0; rt < 4; rt++)
#pragma unroll
            for (int ct = 0; ct < 4; ct++) {
                acc[rt][ct] = __builtin_amdgcn_mfma_f32_16x16x32_bf16(ah[rt], bh[ct], acc[rt][ct], 0, 0, 0);
                acc[rt][ct] = __builtin_amdgcn_mfma_f32_16x16x32_bf16(ah[rt], bl[ct], acc[rt][ct], 0, 0, 0);
                acc[rt][ct] = __builtin_amdgcn_mfma_f32_16x16x32_bf16(al[rt], bh[ct], acc[rt][ct], 0, 0, 0);
            }
    }
#pragma unroll
    for (int rt = 0; rt < 4; rt++) {
        int rbase = gr0 + wrow + rt * 16 + quad * 4;
#pragma unroll
        for (int reg = 0; reg < 4; reg++) {
            int row = rbase + reg;
            if (row >= NNODE) continue;
#pragma unroll
            for (int ct = 0; ct < 4; ct++) {
                int c = cb0 + wcol + ct * 16 + l16;
                float x = acc[rt][ct][reg] + bias[c];
                float g = 1.f / (1.f + __expf(-x));
                size_t idx = (size_t)row * F3 + c;
                float pf = bf2f(pfh[idx]) + bf2f(pfl[idx]);
                float o = outb[idx];
                dout[(size_t)row * 768 + outoff + c] = g * o + (1.f - g) * pf;
            }
        }
    }
}

// ---------------- launch ----------------
extern "C" void kernel_launch(void* const* d_in, const int* in_sizes, int n_in,
                              void* d_out, int out_size, void* d_ws, size_t ws_size,
                              hipStream_t stream) {
    const int* ent_adj = (const int*)d_in[0];
    const int* rel_adj = (const int*)d_in[1];
    const int* adj_list = (const int*)d_in[4];
    const int* r_index = (const int*)d_in[5];
    const float* r_val = (const float*)d_in[6];
    const float* ent_emb = (const float*)d_in[9];
    const float* rel_emb = (const float*)d_in[10];
    const float* e_attn = (const float*)d_in[11];
    const float* e_gate = (const float*)d_in[12];
    const float* e_proxy = (const float*)d_in[13];
    const float* e_bias = (const float*)d_in[14];
    const float* r_attn = (const float*)d_in[15];
    const float* r_gate = (const float*)d_in[16];
    const float* r_proxy = (const float*)d_in[17];
    const float* r_bias = (const float*)d_in[18];
    float* out = (float*)d_out;

    char* ws = (char*)d_ws;
    size_t off = 0;
    auto alloc = [&](size_t bytes) -> void* {
        off = (off + 255) & ~(size_t)255;
        void* p = ws + off;
        off += bytes;
        return p;
    };

    int* degcur = (int*)alloc(6 * NNODE * sizeof(int));
    int* degA = degcur, *curA = degcur + NNODE;
    int* degE = degcur + 2 * NNODE, *curE = degcur + 3 * NNODE;
    int* degR = degcur + 4 * NNODE, *curR = degcur + 5 * NNODE;
    int* offA = (int*)alloc((NNODE + 1) * sizeof(int));
    int* offE = (int*)alloc((NNODE + 1) * sizeof(int));
    int* offR = (int*)alloc((NNODE + 1) * sizeof(int));
    int* ePack = (int*)alloc(NTRI * sizeof(int));
    float* eSc = (float*)alloc(NTRI * sizeof(float));
    int* eColE = (int*)alloc(NTRI * sizeof(int));
    int* eColR = (int*)alloc(NTRI * sizeof(int));
    float* nrm = (float*)alloc(NREL * sizeof(float));
    float2* attL0 = (float2*)alloc(NREL * sizeof(float2));
    float2* attL1 = (float2*)alloc(NREL * sizeof(float2));
    float* scalev = (float*)alloc(NTRI * sizeof(float));
    float* pnT = (float*)alloc((size_t)F3 * NPROX * sizeof(float));
    ushort_t* gTh = (ushort_t*)alloc((size_t)F3 * F3 * sizeof(ushort_t));
    ushort_t* gTl = (ushort_t*)alloc((size_t)F3 * F3 * sizeof(ushort_t));
    float* pa = (float*)alloc((size_t)NNODE * NPROX * sizeof(float));
    ushort_t* pfh = (ushort_t*)alloc((size_t)NNODE * F3 * sizeof(ushort_t));
    ushort_t* pfl = (ushort_t*)alloc((size_t)NNODE * F3 * sizeof(ushort_t));
    float* out_e = (float*)alloc((size_t)NNODE * F3 * sizeof(float));
    float* out_r = (float*)alloc((size_t)NNODE * F3 * sizeof(float));
    (void)ws_size; (void)in_sizes; (void)n_in; (void)out_size;

    hipMemsetAsync(degcur, 0, 6 * NNODE * sizeof(int), stream);

    int gT = (NTRI + 255) / 256;
    k_count3<<<gT, 256, 0, stream>>>(adj_list, ent_adj, rel_adj, degA, degE, degR);
    k_scan_fast<<<3, 1024, 0, stream>>>(degA, offA, degE, offE, degR, offR);
    k_relprep<<<NREL, 64, 0, stream>>>(rel_emb, e_attn, r_attn, nrm, attL0, attL1);
    k_scale<<<gT, 256, 0, stream>>>(r_index + NTRI, r_val, nrm, scalev);
    k_place3<<<gT, 256, 0, stream>>>(adj_list, adj_list + NTRI, ent_adj, ent_adj + NTRI,
                                     rel_adj, rel_adj + NTRI, r_index + NTRI, scalev,
                                     offA, offE, offR, curA, curE, curR,
                                     ePack, eSc, eColE, eColR);

    k_avg2<<<(2 * NNODE) / 4, 256, 0, stream>>>(offE, eColE, ent_emb, offR, eColR, rel_emb,
                                                out_e, out_r);

    int gW = NNODE / 4;
    k_agg2<<<gW, 256, 0, stream>>>(offA, ePack, eSc, attL0, rel_emb, out_e, out_r, 0);
    k_agg2<<<gW, 256, 0, stream>>>(offA, ePack, eSc, attL1, rel_emb, out_e, out_r, 1);

    dim3 g2(NNODE / 64, F3 / 64);
    dim3 g3((NNODE + 127) / 128, F3 / 128);
    // encoder 1 (ent)
    k_proxyprep<<<NPROX, 64, 0, stream>>>(e_proxy, pnT);
    k_gateprep<<<F3, F3, 0, stream>>>(e_gate, gTh, gTl);
    k_scores<<<NNODE / 64, 256, 0, stream>>>(out_e, pnT, pa);
    k_pf<<<g2, 256, 0, stream>>>(pa, e_proxy, out_e, pfh, pfl);
    k_gate_mfma<<<g3, 256, 0, stream>>>(pfh, pfl, gTh, gTl, e_bias, out_e, out, 0);
    // encoder 2 (rel)
    k_proxyprep<<<NPROX, 64, 0, stream>>>(r_proxy, pnT);
    k_gateprep<<<F3, F3, 0, stream>>>(r_gate, gTh, gTl);
    k_scores<<<NNODE / 64, 256, 0, stream>>>(out_r, pnT, pa);
    k_pf<<<g2, 256, 0, stream>>>(pa, r_proxy, out_r, pfh, pfl);
    k_gate_mfma<<<g3, 256, 0, stream>>>(pfh, pfl, gTh, gTl, r_bias, out_r, out, 384);
}

// Round 4
// 990.686 us; speedup vs baseline: 1.7682x; 1.0685x over previous
//
#include <hip/hip_runtime.h>
#include <cmath>

#define NNODE 40000
#define NREL  2000
#define NTRI  600000
#define DIMK  128
#define F3    384
#define NPROX 64
#define EPSN  1e-12f
#define NSLICE 8
#define SLICE_ROWS (NNODE / NSLICE)

typedef unsigned short ushort_t;
typedef __attribute__((ext_vector_type(8))) short bf16x8;
typedef __attribute__((ext_vector_type(4))) float f32x4;

static __device__ __forceinline__ float waveSum(float v) {
#pragma unroll
    for (int m = 32; m >= 1; m >>= 1) v += __shfl_xor(v, m, 64);
    return v;
}

static __device__ __forceinline__ float bf2f(ushort_t h) {
    return __uint_as_float(((unsigned int)h) << 16);
}

static __device__ __forceinline__ void qreduce4(float4& v) {
#pragma unroll
    for (int m = 16; m <= 32; m <<= 1) {
        v.x += __shfl_xor(v.x, m, 64);
        v.y += __shfl_xor(v.y, m, 64);
        v.z += __shfl_xor(v.z, m, 64);
        v.w += __shfl_xor(v.w, m, 64);
    }
}

// ---------------- CSR build ----------------
__global__ void k_count3(const int* __restrict__ rA, const int* __restrict__ rE,
                         const int* __restrict__ rR, int* __restrict__ dA,
                         int* __restrict__ dE, int* __restrict__ dR) {
    int t = blockIdx.x * 256 + threadIdx.x;
    if (t < NTRI) {
        atomicAdd(&dA[rA[t]], 1);
        atomicAdd(&dE[rE[t]], 1);
        atomicAdd(&dR[rR[t]], 1);
    }
}

__global__ void k_scan_fast(const int* __restrict__ dA, int* __restrict__ oA,
                            const int* __restrict__ dE, int* __restrict__ oE,
                            const int* __restrict__ dR, int* __restrict__ oR) {
    const int* deg = blockIdx.x == 0 ? dA : (blockIdx.x == 1 ? dE : dR);
    int* off = blockIdx.x == 0 ? oA : (blockIdx.x == 1 ? oE : oR);
    __shared__ int wsum[16];
    __shared__ int wpre[16];
    int tid = threadIdx.x;
    int lane = tid & 63, wv = tid >> 6;
    const int CH = 40;
    int base = tid * CH;
    int s = 0;
    for (int i = 0; i < CH; i++) {
        int idx = base + i;
        s += (idx < NNODE) ? deg[idx] : 0;
    }
    int incl = s;
#pragma unroll
    for (int m = 1; m < 64; m <<= 1) {
        int v = __shfl_up(incl, m, 64);
        if (lane >= m) incl += v;
    }
    if (lane == 63) wsum[wv] = incl;
    __syncthreads();
    if (tid < 16) {
        int v = wsum[tid];
#pragma unroll
        for (int m = 1; m < 16; m <<= 1) {
            int u = __shfl_up(v, m, 64);
            if (tid >= m) v += u;
        }
        wpre[tid] = v;
    }
    __syncthreads();
    int waveoff = (wv == 0) ? 0 : wpre[wv - 1];
    int run = waveoff + incl - s;
    for (int i = 0; i < CH; i++) {
        int idx = base + i;
        if (idx < NNODE) {
            off[idx] = run;
            run += deg[idx];
        }
    }
    if (tid == 0) off[NNODE] = wpre[15];
}

// XCD-sliced payload placement: slice = blockIdx&7 (round-robin XCD heuristic).
// Each slice writes a private contiguous CSR range -> no cross-XCD dirty-line
// sharing -> writeback ~= ideal. scale computed inline (k_scale eliminated).
__global__ __launch_bounds__(256) void k_place_sliced(
    const int* __restrict__ rA, const int* __restrict__ cA,
    const int* __restrict__ rE, const int* __restrict__ cE,
    const int* __restrict__ rR, const int* __restrict__ cR,
    const int* __restrict__ ridx, const float* __restrict__ rval,
    const float* __restrict__ nrm,
    const int* __restrict__ oA, const int* __restrict__ oE, const int* __restrict__ oR,
    int* __restrict__ cntA, int* __restrict__ cntE, int* __restrict__ cntR,
    int2* __restrict__ ePackSc, int* __restrict__ eColE, int* __restrict__ eColR) {
    int slice = blockIdx.x & (NSLICE - 1);
    int t = (blockIdx.x >> 3) * 256 + threadIdx.x;
    if (t >= NTRI) return;
    int lo = slice * SLICE_ROWS;
    int r = rA[t];
    if ((unsigned)(r - lo) < (unsigned)SLICE_ROWS) {
        int rid = ridx[t];
        float v = rval[t];
        float sc = v / fmaxf(fabsf(v) * nrm[rid], EPSN);
        int p = oA[r] + atomicAdd(&cntA[r], 1);
        ePackSc[p] = make_int2(cA[t] | (rid << 16), __float_as_int(sc));
    }
    r = rE[t];
    if ((unsigned)(r - lo) < (unsigned)SLICE_ROWS)
        eColE[oE[r] + atomicAdd(&cntE[r], 1)] = cE[t];
    r = rR[t];
    if ((unsigned)(r - lo) < (unsigned)SLICE_ROWS)
        eColR[oR[r] + atomicAdd(&cntR[r], 1)] = cR[t];
}

// ---------------- small precomputes ----------------
__global__ void k_relprep(const float* __restrict__ rel_emb,
                          const float* __restrict__ e_attn, const float* __restrict__ r_attn,
                          float* __restrict__ nrm, float2* __restrict__ attL0,
                          float2* __restrict__ attL1) {
    int r = blockIdx.x;
    int lane = threadIdx.x;
    float a = rel_emb[r * DIMK + lane];
    float b = rel_emb[r * DIMK + 64 + lane];
    float nn = waveSum(a * a + b * b);
    float d0 = waveSum(a * e_attn[lane] + b * e_attn[64 + lane]);
    float d1 = waveSum(a * e_attn[DIMK + lane] + b * e_attn[DIMK + 64 + lane]);
    float d2 = waveSum(a * r_attn[lane] + b * r_attn[64 + lane]);
    float d3 = waveSum(a * r_attn[DIMK + lane] + b * r_attn[DIMK + 64 + lane]);
    if (lane == 0) {
        nrm[r] = sqrtf(nn);
        attL0[r] = make_float2(d0, d2);
        attL1[r] = make_float2(d1, d3);
    }
}

// both encoders' proxy prep in one dispatch
__global__ void k_proxyprep2(const float* __restrict__ e_proxy, const float* __restrict__ r_proxy,
                             float* __restrict__ pnT_e, float* __restrict__ pnT_r) {
    int enc = blockIdx.x >= NPROX;
    int k = blockIdx.x & (NPROX - 1);
    const float* proxy = enc ? r_proxy : e_proxy;
    float* pnT = enc ? pnT_r : pnT_e;
    int lane = threadIdx.x;
    float v[6];
    float ss = 0.f;
#pragma unroll
    for (int j = 0; j < 6; j++) {
        v[j] = proxy[k * F3 + j * 64 + lane];
        ss += v[j] * v[j];
    }
    ss = waveSum(ss);
    float inv = 1.0f / fmaxf(sqrtf(ss), EPSN);
#pragma unroll
    for (int j = 0; j < 6; j++) pnT[(j * 64 + lane) * NPROX + k] = v[j] * inv;
}

// both encoders' gate prep in one dispatch
__global__ void k_gateprep2(const float* __restrict__ e_gate, const float* __restrict__ r_gate,
                            ushort_t* __restrict__ the, ushort_t* __restrict__ tle,
                            ushort_t* __restrict__ thr, ushort_t* __restrict__ tlr) {
    int enc = blockIdx.x >= F3;
    int k = enc ? blockIdx.x - F3 : blockIdx.x;
    const float* g = enc ? r_gate : e_gate;
    ushort_t* th = enc ? thr : the;
    ushort_t* tl = enc ? tlr : tle;
    int c = threadIdx.x;
    float v = g[(size_t)k * F3 + c];
    unsigned int b = __float_as_uint(v);
    th[(size_t)c * F3 + k] = (ushort_t)(b >> 16);
    float lo = v - __uint_as_float(b & 0xffff0000u);
    tl[(size_t)c * F3 + k] = (ushort_t)(__float_as_uint(lo) >> 16);
}

// ---------------- fused neighbor mean + tanh ----------------
__global__ __launch_bounds__(256) void k_avg2(
    const int* __restrict__ offE, const int* __restrict__ eColE, const float* __restrict__ ent_emb,
    const int* __restrict__ offR, const int* __restrict__ eColR, const float* __restrict__ rel_emb,
    float* __restrict__ out_e, float* __restrict__ out_r) {
    int gw = (blockIdx.x * blockDim.x + threadIdx.x) >> 6;
    int lane = threadIdx.x & 63;
    if (gw >= 2 * NNODE) return;
    bool isR = gw >= NNODE;
    int wid = isR ? gw - NNODE : gw;
    const int* off = isR ? offR : offE;
    const int* ecol = isR ? eColR : eColE;
    const float4* emb4 = (const float4*)(isR ? rel_emb : ent_emb);
    float* outp = isR ? out_r : out_e;
    int q = lane >> 4, ql = lane & 15;
    int e0 = off[wid], e1 = off[wid + 1];
    float4 aA = {0, 0, 0, 0}, aB = {0, 0, 0, 0};
    for (int base = e0; base < e1; base += 64) {
        int n = min(64, e1 - base);
        int mc = (lane < n) ? ecol[base + lane] : -1;
        for (int j = 0; j < n; j += 4) {
            int e = j + q;
            int c = __shfl(mc, e, 64);
            if (e < n) {
                float4 va = emb4[(size_t)c * 32 + ql];
                float4 vb = emb4[(size_t)c * 32 + 16 + ql];
                aA.x += va.x; aA.y += va.y; aA.z += va.z; aA.w += va.w;
                aB.x += vb.x; aB.y += vb.y; aB.z += vb.z; aB.w += vb.w;
            }
        }
    }
    qreduce4(aA);
    qreduce4(aB);
    if (q == 0) {
        float invd = (e1 > e0) ? 1.0f / (float)(e1 - e0) : 0.0f;
        float4* o = (float4*)outp;
        float4 ra = {tanhf(aA.x * invd), tanhf(aA.y * invd), tanhf(aA.z * invd), tanhf(aA.w * invd)};
        float4 rb = {tanhf(aB.x * invd), tanhf(aB.y * invd), tanhf(aB.z * invd), tanhf(aB.w * invd)};
        o[(size_t)wid * 96 + ql] = ra;
        o[(size_t)wid * 96 + 16 + ql] = rb;
    }
}

// ---------------- fused reflection attention aggregation ----------------
__global__ __launch_bounds__(256) void k_agg2(
    const int* __restrict__ off, const int2* __restrict__ ePackSc,
    const float2* __restrict__ attL, const float* __restrict__ rel_emb,
    float* __restrict__ out_e, float* __restrict__ out_r, int lin) {
    int wid = (blockIdx.x * blockDim.x + threadIdx.x) >> 6;
    int lane = threadIdx.x & 63;
    if (wid >= NNODE) return;
    int q = lane >> 4, ql = lane & 15;
    int e0 = off[wid], e1 = off[wid + 1];
    const float4* rel4 = (const float4*)rel_emb;
    const float4* pe4 = (const float4*)out_e;
    const float4* pr4 = (const float4*)out_r;
    int sA = lin * 32 + ql, sB = lin * 32 + 16 + ql;
    float4 aEa = {0, 0, 0, 0}, aEb = {0, 0, 0, 0}, aRa = {0, 0, 0, 0}, aRb = {0, 0, 0, 0};
    float sE = 0.f, sR = 0.f;
    for (int base = e0; base < e1; base += 64) {
        int n = min(64, e1 - base);
        int pk = 0;
        float sc = 0.f, wE = 0.f, wR = 0.f;
        if (lane < n) {
            int2 ps = ePackSc[base + lane];
            pk = ps.x;
            sc = __int_as_float(ps.y);
            float2 a = attL[pk >> 16];
            wE = __expf(sc * a.x);
            wR = __expf(sc * a.y);
        }
        for (int j = 0; j < n; j += 4) {
            int e = j + q;
            int pke = __shfl(pk, e, 64);
            float sce = __shfl(sc, e, 64);
            float wEe = __shfl(wE, e, 64);
            float wRe = __shfl(wR, e, 64);
            int c = pke & 0xFFFF;
            int r = pke >> 16;
            float4 ra = rel4[(size_t)r * 32 + ql];
            float4 rb = rel4[(size_t)r * 32 + 16 + ql];
            float4 fa = pe4[(size_t)c * 96 + sA];
            float4 fb = pe4[(size_t)c * 96 + sB];
            float4 ga = pr4[(size_t)c * 96 + sA];
            float4 gb = pr4[(size_t)c * 96 + sB];
            float tax = sce * ra.x, tay = sce * ra.y, taz = sce * ra.z, taw = sce * ra.w;
            float tbx = sce * rb.x, tby = sce * rb.y, tbz = sce * rb.z, tbw = sce * rb.w;
            float dE = fa.x * tax + fa.y * tay + fa.z * taz + fa.w * taw +
                       fb.x * tbx + fb.y * tby + fb.z * tbz + fb.w * tbw;
            float dR = ga.x * tax + ga.y * tay + ga.z * taz + ga.w * taw +
                       gb.x * tbx + gb.y * tby + gb.z * tbz + gb.w * tbw;
#pragma unroll
            for (int m = 1; m <= 8; m <<= 1) {
                dE += __shfl_xor(dE, m, 64);
                dR += __shfl_xor(dR, m, 64);
            }
            dE *= 2.f;
            dR *= 2.f;
            aEa.x += wEe * (fa.x - dE * tax);
            aEa.y += wEe * (fa.y - dE * tay);
            aEa.z += wEe * (fa.z - dE * taz);
            aEa.w += wEe * (fa.w - dE * taw);
            aEb.x += wEe * (fb.x - dE * tbx);
            aEb.y += wEe * (fb.y - dE * tby);
            aEb.z += wEe * (fb.z - dE * tbz);
            aEb.w += wEe * (fb.w - dE * tbw);
            aRa.x += wRe * (ga.x - dR * tax);
            aRa.y += wRe * (ga.y - dR * tay);
            aRa.z += wRe * (ga.z - dR * taz);
            aRa.w += wRe * (ga.w - dR * taw);
            aRb.x += wRe * (gb.x - dR * tbx);
            aRb.y += wRe * (gb.y - dR * tby);
            aRb.z += wRe * (gb.z - dR * tbz);
            aRb.w += wRe * (gb.w - dR * tbw);
            sE += wEe;
            sR += wRe;
        }
    }
    qreduce4(aEa);
    qreduce4(aEb);
    qreduce4(aRa);
    qreduce4(aRb);
#pragma unroll
    for (int m = 16; m <= 32; m <<= 1) {
        sE += __shfl_xor(sE, m, 64);
        sR += __shfl_xor(sR, m, 64);
    }
    if (q == 0) {
        float iE = (e1 > e0) ? 1.f / sE : 0.f;
        float4* o = (float4*)out_e;
        float4 wa = {tanhf(aEa.x * iE), tanhf(aEa.y * iE), tanhf(aEa.z * iE), tanhf(aEa.w * iE)};
        float4 wb = {tanhf(aEb.x * iE), tanhf(aEb.y * iE), tanhf(aEb.z * iE), tanhf(aEb.w * iE)};
        o[(size_t)wid * 96 + (lin + 1) * 32 + ql] = wa;
        o[(size_t)wid * 96 + (lin + 1) * 32 + 16 + ql] = wb;
    } else if (q == 1) {
        float iR = (e1 > e0) ? 1.f / sR : 0.f;
        float4* o = (float4*)out_r;
        float4 wa = {tanhf(aRa.x * iR), tanhf(aRa.y * iR), tanhf(aRa.z * iR), tanhf(aRa.w * iR)};
        float4 wb = {tanhf(aRb.x * iR), tanhf(aRb.y * iR), tanhf(aRb.z * iR), tanhf(aRb.w * iR)};
        o[(size_t)wid * 96 + (lin + 1) * 32 + ql] = wa;
        o[(size_t)wid * 96 + (lin + 1) * 32 + 16 + ql] = wb;
    }
}

// ---------------- epilogue (z = encoder) ----------------
__global__ void k_scores(const float* __restrict__ out_e, const float* __restrict__ out_r,
                         const float* __restrict__ pnT_e, const float* __restrict__ pnT_r,
                         float* __restrict__ pa_e, float* __restrict__ pa_r) {
    const float* outb = blockIdx.z ? out_r : out_e;
    const float* pnT = blockIdx.z ? pnT_r : pnT_e;
    float* pa = blockIdx.z ? pa_r : pa_e;
    __shared__ __align__(16) float As[16][68];
    __shared__ __align__(16) float Bs[16][68];
    __shared__ float Ss[64][65];
    __shared__ float rnS[64];
    int tid = threadIdx.x;
    int row0 = blockIdx.x * 64;
    int kk = tid & 15, rr = tid >> 4;
    int cb = tid & 63, kb = tid >> 6;
    int tx = tid & 15, ty = tid >> 4;
    int c0 = tx * 4, r0 = ty * 4;
    float acc[4][4] = {};
    float ssp[4] = {};
    for (int k0 = 0; k0 < F3; k0 += 16) {
#pragma unroll
        for (int u = 0; u < 4; u++) {
            int r = rr + u * 16;
            float v = outb[(size_t)(row0 + r) * F3 + k0 + kk];
            As[kk][r] = v;
            ssp[u] += v * v;
        }
#pragma unroll
        for (int u = 0; u < 4; u++) {
            int k = kb + u * 4;
            Bs[k][cb] = pnT[(size_t)(k0 + k) * NPROX + cb];
        }
        __syncthreads();
#pragma unroll
        for (int k = 0; k < 16; k++) {
            float4 av = *(const float4*)&As[k][r0];
            float4 bv = *(const float4*)&Bs[k][c0];
            float a[4] = {av.x, av.y, av.z, av.w};
            float b[4] = {bv.x, bv.y, bv.z, bv.w};
#pragma unroll
            for (int i = 0; i < 4; i++)
#pragma unroll
                for (int j = 0; j < 4; j++) acc[i][j] += a[i] * b[j];
        }
        __syncthreads();
    }
#pragma unroll
    for (int u = 0; u < 4; u++) {
        float ss = ssp[u];
#pragma unroll
        for (int m = 1; m < 16; m <<= 1) ss += __shfl_xor(ss, m, 64);
        if (kk == 0) rnS[rr + u * 16] = 1.0f / fmaxf(sqrtf(ss), EPSN);
    }
    __syncthreads();
#pragma unroll
    for (int i = 0; i < 4; i++) {
        float rn = rnS[r0 + i];
#pragma unroll
        for (int j = 0; j < 4; j++) Ss[r0 + i][c0 + j] = acc[i][j] * rn;
    }
    __syncthreads();
    if (tid < 64) {
        int r = tid;
        float m = -1e30f;
        for (int c = 0; c < 64; c++) m = fmaxf(m, Ss[r][c]);
        float s = 0.f;
        for (int c = 0; c < 64; c++) s += expf(Ss[r][c] - m);
        float inv = 1.f / s;
        float* po = pa + (size_t)(row0 + r) * NPROX;
        for (int c = 0; c < 64; c++) po[c] = expf(Ss[r][c] - m) * inv;
    }
}

__global__ void k_pf(const float* __restrict__ pa_e, const float* __restrict__ pa_r,
                     const float* __restrict__ e_proxy, const float* __restrict__ r_proxy,
                     const float* __restrict__ out_e, const float* __restrict__ out_r,
                     ushort_t* __restrict__ pfh_e, ushort_t* __restrict__ pfl_e,
                     ushort_t* __restrict__ pfh_r, ushort_t* __restrict__ pfl_r) {
    const float* pa = blockIdx.z ? pa_r : pa_e;
    const float* proxy = blockIdx.z ? r_proxy : e_proxy;
    const float* outb = blockIdx.z ? out_r : out_e;
    ushort_t* pfh = blockIdx.z ? pfh_r : pfh_e;
    ushort_t* pfl = blockIdx.z ? pfl_r : pfl_e;
    __shared__ __align__(16) float As[16][68];
    __shared__ __align__(16) float Bs[16][68];
    int tid = threadIdx.x;
    int row0 = blockIdx.x * 64;
    int col0 = blockIdx.y * 64;
    int kk = tid & 15, rr = tid >> 4;
    int cb = tid & 63, kb = tid >> 6;
    int tx = tid & 15, ty = tid >> 4;
    int c0 = tx * 4, r0 = ty * 4;
    float acc[4][4] = {};
    for (int k0 = 0; k0 < NPROX; k0 += 16) {
#pragma unroll
        for (int u = 0; u < 4; u++) {
            int r = rr + u * 16;
            As[kk][r] = pa[(size_t)(row0 + r) * NPROX + k0 + kk];
        }
#pragma unroll
        for (int u = 0; u < 4; u++) {
            int k = kb + u * 4;
            Bs[k][cb] = proxy[(size_t)(k0 + k) * F3 + col0 + cb];
        }
        __syncthreads();
#pragma unroll
        for (int k = 0; k < 16; k++) {
            float4 av = *(const float4*)&As[k][r0];
            float4 bv = *(const float4*)&Bs[k][c0];
            float a[4] = {av.x, av.y, av.z, av.w};
            float b[4] = {bv.x, bv.y, bv.z, bv.w};
#pragma unroll
            for (int i = 0; i < 4; i++)
#pragma unroll
                for (int j = 0; j < 4; j++) acc[i][j] += a[i] * b[j];
        }
        __syncthreads();
    }
#pragma unroll
    for (int i = 0; i < 4; i++)
#pragma unroll
        for (int j = 0; j < 4; j++) {
            size_t idx = (size_t)(row0 + r0 + i) * F3 + col0 + c0 + j;
            float v = outb[idx] - acc[i][j];
            unsigned int b = __float_as_uint(v);
            pfh[idx] = (ushort_t)(b >> 16);
            float lo = v - __uint_as_float(b & 0xffff0000u);
            pfl[idx] = (ushort_t)(__float_as_uint(lo) >> 16);
        }
}

__global__ __launch_bounds__(256) void k_gate_mfma(
    const ushort_t* __restrict__ pfh_e, const ushort_t* __restrict__ pfl_e,
    const ushort_t* __restrict__ pfh_r, const ushort_t* __restrict__ pfl_r,
    const ushort_t* __restrict__ gTh_e, const ushort_t* __restrict__ gTl_e,
    const ushort_t* __restrict__ gTh_r, const ushort_t* __restrict__ gTl_r,
    const float* __restrict__ e_bias, const float* __restrict__ r_bias,
    const float* __restrict__ out_e, const float* __restrict__ out_r,
    float* __restrict__ dout) {
    const ushort_t* pfh = blockIdx.z ? pfh_r : pfh_e;
    const ushort_t* pfl = blockIdx.z ? pfl_r : pfl_e;
    const ushort_t* gTh = blockIdx.z ? gTh_r : gTh_e;
    const ushort_t* gTl = blockIdx.z ? gTl_r : gTl_e;
    const float* bias = blockIdx.z ? r_bias : e_bias;
    const float* outb = blockIdx.z ? out_r : out_e;
    int outoff = blockIdx.z ? F3 : 0;
    __shared__ __align__(16) ushort_t AsH[128 * 40];
    __shared__ __align__(16) ushort_t AsL[128 * 40];
    int tid = threadIdx.x;
    int w = tid >> 6, lane = tid & 63;
    int quad = lane >> 4, l16 = lane & 15;
    int wrow = (w >> 1) * 64, wcol = (w & 1) * 64;
    int gr0 = blockIdx.x * 128;
    int cb0 = blockIdx.y * 128;
    f32x4 acc[4][4];
#pragma unroll
    for (int rt = 0; rt < 4; rt++)
#pragma unroll
        for (int ct = 0; ct < 4; ct++) acc[rt][ct] = (f32x4){0.f, 0.f, 0.f, 0.f};

    int srow = tid >> 2, sseg = tid & 3;
    for (int k0 = 0; k0 < F3; k0 += 32) {
        __syncthreads();
#pragma unroll
        for (int u = 0; u < 2; u++) {
            int row = srow + u * 64;
            int gr = gr0 + row;
            uint4 vh = {0, 0, 0, 0}, vl = {0, 0, 0, 0};
            if (gr < NNODE) {
                vh = *(const uint4*)&pfh[(size_t)gr * F3 + k0 + sseg * 8];
                vl = *(const uint4*)&pfl[(size_t)gr * F3 + k0 + sseg * 8];
            }
            *(uint4*)&AsH[row * 40 + sseg * 8] = vh;
            *(uint4*)&AsL[row * 40 + sseg * 8] = vl;
        }
        __syncthreads();
        bf16x8 ah[4], al[4], bh[4], bl[4];
#pragma unroll
        for (int rt = 0; rt < 4; rt++) {
            int ar = wrow + rt * 16 + l16;
            ah[rt] = *(const bf16x8*)&AsH[ar * 40 + quad * 8];
            al[rt] = *(const bf16x8*)&AsL[ar * 40 + quad * 8];
        }
#pragma unroll
        for (int ct = 0; ct < 4; ct++) {
            int bc = cb0 + wcol + ct * 16 + l16;
            bh[ct] = *(const bf16x8*)&gTh[(size_t)bc * F3 + k0 + quad * 8];
            bl[ct] = *(const bf16x8*)&gTl[(size_t)bc * F3 + k0 + quad * 8];
        }
#pragma unroll
        for (int rt = 0; rt < 4; rt++)
#pragma unroll
            for (int ct = 0; ct < 4; ct++) {
                acc[rt][ct] = __builtin_amdgcn_mfma_f32_16x16x32_bf16(ah[rt], bh[ct], acc[rt][ct], 0, 0, 0);
                acc[rt][ct] = __builtin_amdgcn_mfma_f32_16x16x32_bf16(ah[rt], bl[ct], acc[rt][ct], 0, 0, 0);
                acc[rt][ct] = __builtin_amdgcn_mfma_f32_16x16x32_bf16(al[rt], bh[ct], acc[rt][ct], 0, 0, 0);
            }
    }
#pragma unroll
    for (int rt = 0; rt < 4; rt++) {
        int rbase = gr0 + wrow + rt * 16 + quad * 4;
#pragma unroll
        for (int reg = 0; reg < 4; reg++) {
            int row = rbase + reg;
            if (row >= NNODE) continue;
#pragma unroll
            for (int ct = 0; ct < 4; ct++) {
                int c = cb0 + wcol + ct * 16 + l16;
                float x = acc[rt][ct][reg] + bias[c];
                float g = 1.f / (1.f + __expf(-x));
                size_t idx = (size_t)row * F3 + c;
                float pf = bf2f(pfh[idx]) + bf2f(pfl[idx]);
                float o = outb[idx];
                dout[(size_t)row * 768 + outoff + c] = g * o + (1.f - g) * pf;
            }
        }
    }
}

// ---------------- launch ----------------
extern "C" void kernel_launch(void* const* d_in, const int* in_sizes, int n_in,
                              void* d_out, int out_size, void* d_ws, size_t ws_size,
                              hipStream_t stream) {
    const int* ent_adj = (const int*)d_in[0];
    const int* rel_adj = (const int*)d_in[1];
    const int* adj_list = (const int*)d_in[4];
    const int* r_index = (const int*)d_in[5];
    const float* r_val = (const float*)d_in[6];
    const float* ent_emb = (const float*)d_in[9];
    const float* rel_emb = (const float*)d_in[10];
    const float* e_attn = (const float*)d_in[11];
    const float* e_gate = (const float*)d_in[12];
    const float* e_proxy = (const float*)d_in[13];
    const float* e_bias = (const float*)d_in[14];
    const float* r_attn = (const float*)d_in[15];
    const float* r_gate = (const float*)d_in[16];
    const float* r_proxy = (const float*)d_in[17];
    const float* r_bias = (const float*)d_in[18];
    float* out = (float*)d_out;

    char* ws = (char*)d_ws;
    size_t off = 0;
    auto alloc = [&](size_t bytes) -> void* {
        off = (off + 255) & ~(size_t)255;
        void* p = ws + off;
        off += bytes;
        return p;
    };

    int* degcur = (int*)alloc(6 * NNODE * sizeof(int));
    int* degA = degcur, *curA = degcur + NNODE;
    int* degE = degcur + 2 * NNODE, *curE = degcur + 3 * NNODE;
    int* degR = degcur + 4 * NNODE, *curR = degcur + 5 * NNODE;
    int* offA = (int*)alloc((NNODE + 1) * sizeof(int));
    int* offE = (int*)alloc((NNODE + 1) * sizeof(int));
    int* offR = (int*)alloc((NNODE + 1) * sizeof(int));
    int2* ePackSc = (int2*)alloc(NTRI * sizeof(int2));
    int* eColE = (int*)alloc(NTRI * sizeof(int));
    int* eColR = (int*)alloc(NTRI * sizeof(int));
    float* nrm = (float*)alloc(NREL * sizeof(float));
    float2* attL0 = (float2*)alloc(NREL * sizeof(float2));
    float2* attL1 = (float2*)alloc(NREL * sizeof(float2));
    float* pnT_e = (float*)alloc((size_t)F3 * NPROX * sizeof(float));
    float* pnT_r = (float*)alloc((size_t)F3 * NPROX * sizeof(float));
    ushort_t* gTh_e = (ushort_t*)alloc((size_t)F3 * F3 * sizeof(ushort_t));
    ushort_t* gTl_e = (ushort_t*)alloc((size_t)F3 * F3 * sizeof(ushort_t));
    ushort_t* gTh_r = (ushort_t*)alloc((size_t)F3 * F3 * sizeof(ushort_t));
    ushort_t* gTl_r = (ushort_t*)alloc((size_t)F3 * F3 * sizeof(ushort_t));
    float* pa_e = (float*)alloc((size_t)NNODE * NPROX * sizeof(float));
    float* pa_r = (float*)alloc((size_t)NNODE * NPROX * sizeof(float));
    ushort_t* pfh_e = (ushort_t*)alloc((size_t)NNODE * F3 * sizeof(ushort_t));
    ushort_t* pfl_e = (ushort_t*)alloc((size_t)NNODE * F3 * sizeof(ushort_t));
    ushort_t* pfh_r = (ushort_t*)alloc((size_t)NNODE * F3 * sizeof(ushort_t));
    ushort_t* pfl_r = (ushort_t*)alloc((size_t)NNODE * F3 * sizeof(ushort_t));
    float* out_e = (float*)alloc((size_t)NNODE * F3 * sizeof(float));
    float* out_r = (float*)alloc((size_t)NNODE * F3 * sizeof(float));
    (void)ws_size; (void)in_sizes; (void)n_in; (void)out_size;

    hipMemsetAsync(degcur, 0, 6 * NNODE * sizeof(int), stream);

    int gT = (NTRI + 255) / 256;
    k_count3<<<gT, 256, 0, stream>>>(adj_list, ent_adj, rel_adj, degA, degE, degR);
    k_scan_fast<<<3, 1024, 0, stream>>>(degA, offA, degE, offE, degR, offR);
    k_relprep<<<NREL, 64, 0, stream>>>(rel_emb, e_attn, r_attn, nrm, attL0, attL1);
    k_place_sliced<<<gT * NSLICE, 256, 0, stream>>>(
        adj_list, adj_list + NTRI, ent_adj, ent_adj + NTRI, rel_adj, rel_adj + NTRI,
        r_index + NTRI, r_val, nrm, offA, offE, offR, curA, curE, curR,
        ePackSc, eColE, eColR);
    k_proxyprep2<<<2 * NPROX, 64, 0, stream>>>(e_proxy, r_proxy, pnT_e, pnT_r);
    k_gateprep2<<<2 * F3, F3, 0, stream>>>(e_gate, r_gate, gTh_e, gTl_e, gTh_r, gTl_r);

    k_avg2<<<(2 * NNODE) / 4, 256, 0, stream>>>(offE, eColE, ent_emb, offR, eColR, rel_emb,
                                                out_e, out_r);

    int gW = NNODE / 4;
    k_agg2<<<gW, 256, 0, stream>>>(offA, ePackSc, attL0, rel_emb, out_e, out_r, 0);
    k_agg2<<<gW, 256, 0, stream>>>(offA, ePackSc, attL1, rel_emb, out_e, out_r, 1);

    dim3 gS(NNODE / 64, 1, 2);
    dim3 gP(NNODE / 64, F3 / 64, 2);
    dim3 gG((NNODE + 127) / 128, F3 / 128, 2);
    k_scores<<<gS, 256, 0, stream>>>(out_e, out_r, pnT_e, pnT_r, pa_e, pa_r);
    k_pf<<<gP, 256, 0, stream>>>(pa_e, pa_r, e_proxy, r_proxy, out_e, out_r,
                                 pfh_e, pfl_e, pfh_r, pfl_r);
    k_gate_mfma<<<gG, 256, 0, stream>>>(pfh_e, pfl_e, pfh_r, pfl_r, gTh_e, gTl_e, gTh_r, gTl_r,
                                        e_bias, r_bias, out_e, out_r, out);
}